// Round 12
// baseline (282.330 us; speedup 1.0000x reference)
//
#include <hip/hip_runtime.h>
#include <hip/hip_bf16.h>
#include <stdint.h>

// B=8, T=4096, D=512, OUT=1. M = B*T = 32768.
// cast; fused gates GEMM (32x32x16 MFMA, FRAGMENT-MAJOR LDS -> linear wave reads,
// ring-2, fused chunk summaries); pass2; pass3 (L0) / pass3+LN+proj fused (L1).

#define MROWS 32768
#define DDIM  512
#define TLEN  4096
#define BSZ   8
#define NCHUNK 64
#define CLEN   64

typedef __attribute__((ext_vector_type(8))) __bf16 bf16x8;
typedef __attribute__((ext_vector_type(16))) float f32x16;
typedef __attribute__((ext_vector_type(4))) unsigned short ushort4_t;

static __device__ __forceinline__ unsigned short f2bf(float f) {
    unsigned int u = __float_as_uint(f);
    u = (u + 0x7FFFu + ((u >> 16) & 1u)) >> 16;   // RNE
    return (unsigned short)u;
}
static __device__ __forceinline__ float bf2f(unsigned short s) {
    return __uint_as_float(((unsigned int)s) << 16);
}
static __device__ __forceinline__ void gload_lds16(const void* gptr, void* ldsp) {
    __builtin_amdgcn_global_load_lds(
        (const __attribute__((address_space(1))) uint32_t*)gptr,
        (__attribute__((address_space(3))) uint32_t*)ldsp,
        16, 0, 0);
}

#define WAITV(n) asm volatile("s_waitcnt vmcnt(" #n ")" ::: "memory")

// ---------------- merged fp32 -> bf16 cast (x + 6 W) ----------------
__global__ __launch_bounds__(256) void cast_all(
    const float4* __restrict__ x,
    const float4* __restrict__ w0, const float4* __restrict__ w1,
    const float4* __restrict__ w2, const float4* __restrict__ w3,
    const float4* __restrict__ w4, const float4* __restrict__ w5,
    ushort4_t* __restrict__ xb, ushort4_t* __restrict__ wb)
{
    int i = blockIdx.x * 256 + threadIdx.x;    // 0 .. 4587519
    float4 v;
    ushort4_t* dst;
    if (i < 4194304) {
        v = x[i];
        dst = xb + i;
    } else {
        int j = i - 4194304;
        int wsel = j >> 16;
        int rem = j & 65535;
        const float4* src = (wsel == 0) ? w0 : (wsel == 1) ? w1 : (wsel == 2) ? w2
                          : (wsel == 3) ? w3 : (wsel == 4) ? w4 : w5;
        v = src[rem];
        dst = wb + j;
    }
    ushort4_t o;
    o.x = f2bf(v.x); o.y = f2bf(v.y); o.z = f2bf(v.z); o.w = f2bf(v.w);
    *dst = o;
}

// ---------------- fused gate GEMM + chunk-summary epilogue ----------------
// 256 thr / 4 waves (2m x 2n), wave tile 64x32 via 32x32x16 MFMA (2 m-frags x
// 3 gates, acc 6x f32x16 = 96 AGPR). BM=128, BN=64, BK=64; 8 K-tiles.
// LDS: ring-2 x (A 16KB + 3x B 8KB = 40KB) = 80KB, FRAGMENT-MAJOR:
//   slot s (16B) in a region holds (group g = s>>8, ks = (s>>6)&3, lane l = s&63)
//   containing element [row = g*32 + (l&31)][kcol = (2*ks + (l>>5))*8 bf16].
// Wave reads are LINEAR (lane l -> base + l*16B): bank-perfect, zero addr math.
// Rationale: rounds 9-11 showed the 32-row x 2-chunk row-major read pattern is
// structurally 4 cyc/read conflicted under ANY XOR; rounds 6-8's 0-conflict
// patterns and the canonical linear read avoid it.
// Staging source (G21): row = q*32 + (tid&31), col = (tid>>5)*8 -- the LDS dest
// stays linear (identical dest offsets to round 11; only sources changed).
// Per K-tile: {STAGE t+1 (10 gload_lds); vmcnt(10) counted; barrier;
//              4x [5 linear ds_read_b128; setprio(1); 6 MFMA; setprio(0)]; barrier}.
__global__ __launch_bounds__(256, 2) void gates_gemm(
    const unsigned short* __restrict__ X,
    const unsigned short* __restrict__ Wf,
    const unsigned short* __restrict__ Wi,
    const unsigned short* __restrict__ Wh,
    const float* __restrict__ bf_, const float* __restrict__ bi_,
    const float* __restrict__ bh_,
    unsigned int* __restrict__ au_out,
    float* __restrict__ Asum, float* __restrict__ Usum)
{
    __shared__ __align__(16) unsigned short lds[2 * 20480];   // 80 KB

    const int tid  = threadIdx.x;
    const int lane = tid & 63;
    const int wave = tid >> 6;                 // 0..3
    const int wm = wave >> 1;                  // 0..1 : 64-row strip (= one chunk)
    const int wn = wave & 1;                   // 0..1 : 32-col strip
    const int ln31 = lane & 31;
    const int kh = lane >> 5;                  // k-half within 16-k MFMA step

    // XCD-aware bijective swizzle: 2048 blocks; 8 bx of one by adjacent per XCD.
    const int w = blockIdx.x;
    const int xcd = w & 7;
    const int s = w >> 3;                      // 0..255
    const int by = xcd * 32 + (s >> 3);        // 0..255
    const int bx = s & 7;                      // 0..7
    const int mblk = by * 128;
    const int nblk = bx * 64;

    // staging: thread t writes 16B slots {q*256+t}; content row = q*32 + (t&31),
    // kcol = (t>>5)*8 within the K-tile. Dest linear: ushort off = (q*256+t)*8.
    const int row_l = tid & 31;
    const int colg  = (tid >> 5) << 3;         // bf16 units
    const int tid8  = tid * 8;                 // linear LDS dest (ushorts)
    const unsigned short* gA0 = X + (size_t)(mblk + row_l) * 512 + colg;
    const unsigned short* gA1 = X + (size_t)(mblk + 32 + row_l) * 512 + colg;
    const unsigned short* gA2 = X + (size_t)(mblk + 64 + row_l) * 512 + colg;
    const unsigned short* gA3 = X + (size_t)(mblk + 96 + row_l) * 512 + colg;
    const unsigned short* gF0 = Wf + (size_t)(nblk + row_l) * 512 + colg;
    const unsigned short* gF1 = Wf + (size_t)(nblk + 32 + row_l) * 512 + colg;
    const unsigned short* gI0 = Wi + (size_t)(nblk + row_l) * 512 + colg;
    const unsigned short* gI1 = Wi + (size_t)(nblk + 32 + row_l) * 512 + colg;
    const unsigned short* gH0 = Wh + (size_t)(nblk + row_l) * 512 + colg;
    const unsigned short* gH1 = Wh + (size_t)(nblk + 32 + row_l) * 512 + colg;

    // linear read vaddr (ushorts): lane*8; all region bases are immediates.
    const int lane16 = lane * 8;

    f32x16 accF[2], accI[2], accH[2];
#pragma unroll
    for (int mi = 0; mi < 2; ++mi) {
#pragma unroll
        for (int e = 0; e < 16; ++e) { accF[mi][e] = 0.f; accI[mi][e] = 0.f; accH[mi][e] = 0.f; }
    }

#define STAGE(bb) do { \
    gload_lds16(gA0, lds + (bb) + tid8);             \
    gload_lds16(gA1, lds + (bb) + 2048  + tid8);     \
    gload_lds16(gA2, lds + (bb) + 4096  + tid8);     \
    gload_lds16(gA3, lds + (bb) + 6144  + tid8);     \
    gload_lds16(gF0, lds + (bb) + 8192  + tid8);     \
    gload_lds16(gF1, lds + (bb) + 10240 + tid8);     \
    gload_lds16(gI0, lds + (bb) + 12288 + tid8);     \
    gload_lds16(gI1, lds + (bb) + 14336 + tid8);     \
    gload_lds16(gH0, lds + (bb) + 16384 + tid8);     \
    gload_lds16(gH1, lds + (bb) + 18432 + tid8);     \
    gA0 += 64; gA1 += 64; gA2 += 64; gA3 += 64; gF0 += 64; \
    gF1 += 64; gI0 += 64; gI1 += 64; gH0 += 64; gH1 += 64; } while (0)

    STAGE(0);   // tile 0 -> buf0

#pragma unroll
    for (int t = 0; t < 8; ++t) {
        if (t < 7) {
            STAGE(((t + 1) & 1) * 20480);   // dest protected by t-1's end barrier
            WAITV(10);                       // tile t's 10 loads done; t+1 in flight
        } else {
            WAITV(0);
        }
        __builtin_amdgcn_s_barrier();
        __builtin_amdgcn_sched_barrier(0);

        const unsigned short* cb = lds + (t & 1) * 20480;
#pragma unroll
        for (int ks = 0; ks < 4; ++ks) {
            // A regions: ((wm*2+mi)*4+ks)*512 ushorts; B: gate_base + (wn*4+ks)*512
            bf16x8 af0 = *reinterpret_cast<const bf16x8*>(cb + (wm * 8 + ks) * 512 + lane16);
            bf16x8 bF  = *reinterpret_cast<const bf16x8*>(cb + 8192  + (wn * 4 + ks) * 512 + lane16);
            bf16x8 af1 = *reinterpret_cast<const bf16x8*>(cb + (wm * 8 + 4 + ks) * 512 + lane16);
            bf16x8 bI  = *reinterpret_cast<const bf16x8*>(cb + 12288 + (wn * 4 + ks) * 512 + lane16);
            bf16x8 bH  = *reinterpret_cast<const bf16x8*>(cb + 16384 + (wn * 4 + ks) * 512 + lane16);
            __builtin_amdgcn_s_setprio(1);
            accF[0] = __builtin_amdgcn_mfma_f32_32x32x16_bf16(af0, bF, accF[0], 0, 0, 0);
            accF[1] = __builtin_amdgcn_mfma_f32_32x32x16_bf16(af1, bF, accF[1], 0, 0, 0);
            accI[0] = __builtin_amdgcn_mfma_f32_32x32x16_bf16(af0, bI, accI[0], 0, 0, 0);
            accI[1] = __builtin_amdgcn_mfma_f32_32x32x16_bf16(af1, bI, accI[1], 0, 0, 0);
            accH[0] = __builtin_amdgcn_mfma_f32_32x32x16_bf16(af0, bH, accH[0], 0, 0, 0);
            accH[1] = __builtin_amdgcn_mfma_f32_32x32x16_bf16(af1, bH, accH[1], 0, 0, 0);
            __builtin_amdgcn_s_setprio(0);
        }
        __builtin_amdgcn_sched_barrier(0);
        __builtin_amdgcn_s_barrier();   // protects cb from next iteration's STAGE
        __builtin_amdgcn_sched_barrier(0);
    }
#undef STAGE

    // ---- epilogue: gates + packed au + full-chunk summary ----
    // C/D 32x32: col = lane&31 (n), row = (reg&3) + 8*(reg>>2) + 4*(lane>>5).
    const int n = nblk + wn * 32 + ln31;
    const float bfv = bf_[n], biv = bi_[n], bhv = bh_[n];
    const bool up = (lane & 32) != 0;
    float ca = 1.f, cu = 0.f;                  // chunk compose (64 rows, ascending)
#pragma unroll
    for (int mi = 0; mi < 2; ++mi) {
#pragma unroll
        for (int j = 0; j < 4; ++j) {          // 8-row block: rows mi*32 + 8j + 4*kh + r
            float sa = 1.f, su = 0.f;
#pragma unroll
            for (int r = 0; r < 4; ++r) {
                const int reg = 4 * j + r;
                const int m = mblk + wm * 64 + mi * 32 + 8 * j + 4 * kh + r;
                float zf = accF[mi][reg] + bfv;
                float zi = accI[mi][reg] + biv;
                float zh = accH[mi][reg] + bhv;
                float ef = __expf(-zf);
                float ei = __expf(-zi);
                float inv = __frcp_rn(2.0f + ef + ei);
                float av = (1.0f + ei) * inv;
                float uv = (1.0f + ef) * inv * zh;
                au_out[(size_t)m * 512 + n] =
                    ((unsigned int)f2bf(uv) << 16) | (unsigned int)f2bf(av);
                su = av * su + uv; sa *= av;   // compose rows ascending
            }
            // combine kh halves (rows +0..3 then +4..7) via xor-32 exchange
            float oa = __shfl_xor(sa, 32), ou = __shfl_xor(su, 32);
            float ta = sa * oa;
            float tu = up ? (sa * ou + su) : (oa * su + ou);
            // chunk := blk applied after chunk
            cu = ta * cu + tu; ca = ca * ta;
        }
    }
    if (lane < 32) {
        size_t ci = (size_t)(by * 2 + wm) * 512 + n;
        Asum[ci] = ca;
        Usum[ci] = cu;
    }
}

// ---------------- chunk-prefix (pass2) ----------------
__global__ void scan_pass2(const float4* __restrict__ Asum, const float4* __restrict__ Usum,
                           float4* __restrict__ Hinit) {
    int t = blockIdx.x * 256 + threadIdx.x;  // 0..1023
    int d4 = t & 127;
    int b = t >> 7;
    float4 h = {0.f, 0.f, 0.f, 0.f};
    for (int c = 0; c < NCHUNK; ++c) {
        size_t idx = (size_t)(b * NCHUNK + c) * 128 + d4;
        Hinit[idx] = h;
        float4 A = Asum[idx]; float4 U = Usum[idx];
        h.x = A.x * h.x + U.x; h.y = A.y * h.y + U.y;
        h.z = A.z * h.z + U.z; h.w = A.w * h.w + U.w;
    }
}

// ---------------- pass3 (layer 0): scan -> bf16 h ----------------
__global__ void scan_pass3(const uint4* __restrict__ au,
                           const float4* __restrict__ Hinit,
                           ushort4_t* __restrict__ hout) {
    int gid = blockIdx.x * 256 + threadIdx.x;   // 0..65535
    int d4 = gid & 127;
    int c  = (gid >> 7) & 63;
    int b  = gid >> 13;
    size_t base = (size_t)(b * TLEN + c * CLEN) * 128 + d4;
    size_t s4 = (size_t)(b * NCHUNK + c) * 128 + d4;
    float4 h0 = Hinit[s4];
    float h[4] = {h0.x, h0.y, h0.z, h0.w};
#pragma unroll 4
    for (int l = 0; l < CLEN; ++l) {
        size_t idx = base + (size_t)l * 128;
        uint4 v = au[idx];
        unsigned int vv[4] = {v.x, v.y, v.z, v.w};
        ushort4_t o;
#pragma unroll
        for (int j = 0; j < 4; ++j) {
            float av = __uint_as_float(vv[j] << 16);
            float uv = __uint_as_float(vv[j] & 0xFFFF0000u);
            h[j] = av * h[j] + uv;
            o[j] = f2bf(h[j]);
        }
        hout[idx] = o;
    }
}

// ---------------- pass3+residual+LN+proj fused (layer 1) ----------------
__global__ __launch_bounds__(128) void scan3_final(
    const uint4* __restrict__ au, const float4* __restrict__ Hinit,
    const float4* __restrict__ x4,
    const float* __restrict__ g, const float* __restrict__ bvec,
    const float* __restrict__ Wout, const float* __restrict__ bout,
    float* __restrict__ out)
{
    const int blk = blockIdx.x;            // 0..511 = b*64 + c
    const int b = blk >> 6, c = blk & 63;
    const int d4 = threadIdx.x;            // 0..127
    const int lane = threadIdx.x & 63;
    const int wv = threadIdx.x >> 6;

    float4 h0 = Hinit[(size_t)blk * 128 + d4];
    float h[4] = {h0.x, h0.y, h0.z, h0.w};
    float4 g4 = reinterpret_cast<const float4*>(g)[d4];
    float4 b4 = reinterpret_cast<const float4*>(bvec)[d4];
    float4 w4 = reinterpret_cast<const float4*>(Wout)[d4];
    const float ga[4] = {g4.x, g4.y, g4.z, g4.w};
    const float ba[4] = {b4.x, b4.y, b4.z, b4.w};
    const float wa[4] = {w4.x, w4.y, w4.z, w4.w};
    const float bo = bout[0];

    __shared__ float redS[2], redQ[2], redP[2];
    size_t base = ((size_t)b * TLEN + c * CLEN) * 128 + d4;

    for (int l = 0; l < CLEN; ++l) {
        size_t idx = base + (size_t)l * 128;
        uint4 v = au[idx];
        float4 xr = x4[idx];
        const unsigned int vv[4] = {v.x, v.y, v.z, v.w};
        const float xa[4] = {xr.x, xr.y, xr.z, xr.w};
        float r[4];
        float sfl = 0.f, q = 0.f;
#pragma unroll
        for (int j = 0; j < 4; ++j) {
            float av = __uint_as_float(vv[j] << 16);
            float uv = __uint_as_float(vv[j] & 0xFFFF0000u);
            h[j] = av * h[j] + uv;
            float hv = h[j];
            if (hv != hv) hv = xa[j];          // NaN fallback
            float rr = xa[j] + hv;
            r[j] = rr;
            sfl += rr; q += rr * rr;
        }
#pragma unroll
        for (int m = 32; m >= 1; m >>= 1) {
            sfl += __shfl_xor(sfl, m);
            q += __shfl_xor(q, m);
        }
        if (lane == 0) { redS[wv] = sfl; redQ[wv] = q; }
        __syncthreads();
        float st = redS[0] + redS[1];
        float qt = redQ[0] + redQ[1];
        float mu = st * (1.0f / 512.0f);
        float var = qt * (1.0f / 512.0f) - mu * mu;
        float rstd = rsqrtf(var + 1e-5f);
        float p = 0.f;
#pragma unroll
        for (int j = 0; j < 4; ++j)
            p += ((r[j] - mu) * rstd * ga[j] + ba[j]) * wa[j];
#pragma unroll
        for (int m = 32; m >= 1; m >>= 1) p += __shfl_xor(p, m);
        if (lane == 0) redP[wv] = p;
        __syncthreads();
        if (threadIdx.x == 0)
            out[(size_t)b * TLEN + c * CLEN + l] = redP[0] + redP[1] + bo;
    }
}

extern "C" void kernel_launch(void* const* d_in, const int* in_sizes, int n_in,
                              void* d_out, int out_size, void* d_ws, size_t ws_size,
                              hipStream_t stream) {
    const float* x    = (const float*)d_in[0];
    const float* Wf0  = (const float*)d_in[1];  const float* bf0 = (const float*)d_in[2];
    const float* Wi0  = (const float*)d_in[3];  const float* bi0 = (const float*)d_in[4];
    const float* Wh0  = (const float*)d_in[5];  const float* bh0 = (const float*)d_in[6];
    const float* Wf1  = (const float*)d_in[7];  const float* bf1 = (const float*)d_in[8];
    const float* Wi1  = (const float*)d_in[9];  const float* bi1 = (const float*)d_in[10];
    const float* Wh1  = (const float*)d_in[11]; const float* bh1 = (const float*)d_in[12];
    const float* ln_g = (const float*)d_in[13]; const float* ln_b = (const float*)d_in[14];
    const float* W_out = (const float*)d_in[15]; const float* b_out = (const float*)d_in[16];

    char* ws = (char*)d_ws;
    unsigned short* Xb = (unsigned short*)ws;  ws += (size_t)MROWS * DDIM * 2;   // 32 MB
    unsigned short* Wball = (unsigned short*)ws;
    unsigned short* Wb[6];
    for (int i = 0; i < 6; ++i) { Wb[i] = (unsigned short*)ws; ws += (size_t)DDIM * DDIM * 2; }
    unsigned int* aubuf = (unsigned int*)ws; ws += (size_t)MROWS * DDIM * 4;     // 64 MB packed a|u
    float* Asum = (float*)ws;  ws += (size_t)BSZ * NCHUNK * DDIM * 4;            // 1 MB
    float* Usum = (float*)ws;  ws += (size_t)BSZ * NCHUNK * DDIM * 4;
    float* Hinit = (float*)ws; ws += (size_t)BSZ * NCHUNK * DDIM * 4;
    unsigned short* h0b = (unsigned short*)ws; ws += (size_t)MROWS * DDIM * 2;   // 32 MB

    // merged casts
    cast_all<<<17920, 256, 0, stream>>>(
        (const float4*)x, (const float4*)Wf0, (const float4*)Wi0, (const float4*)Wh0,
        (const float4*)Wf1, (const float4*)Wi1, (const float4*)Wh1,
        (ushort4_t*)Xb, (ushort4_t*)Wball);

    // ---- layer 0 ----
    gates_gemm<<<2048, 256, 0, stream>>>(Xb, Wb[0], Wb[1], Wb[2], bf0, bi0, bh0,
                                         aubuf, Asum, Usum);
    scan_pass2<<<4, 256, 0, stream>>>((const float4*)Asum, (const float4*)Usum, (float4*)Hinit);
    scan_pass3<<<256, 256, 0, stream>>>((const uint4*)aubuf, (const float4*)Hinit, (ushort4_t*)h0b);

    // ---- layer 1 ----
    gates_gemm<<<2048, 256, 0, stream>>>(h0b, Wb[3], Wb[4], Wb[5], bf1, bi1, bh1,
                                         aubuf, Asum, Usum);
    scan_pass2<<<4, 256, 0, stream>>>((const float4*)Asum, (const float4*)Usum, (float4*)Hinit);
    scan3_final<<<512, 128, 0, stream>>>((const uint4*)aubuf, (const float4*)Hinit,
                                         (const float4*)x, ln_g, ln_b, W_out, b_out,
                                         (float*)d_out);
}

// Round 13
// 253.201 us; speedup vs baseline: 1.1150x; 1.1150x over previous
//
#include <hip/hip_runtime.h>
#include <hip/hip_bf16.h>
#include <stdint.h>

// B=8, T=4096, D=512, OUT=1. M = B*T = 32768.
// cast_perm (X,W -> staging-slot-order bf16); fused gates GEMM (fragment-major
// LDS, linear staged + linear reads, 0 conflicts); pass2; pass3 (permuted h0);
// scan3_final (L1).
//
// Permuted layout (16B slots): S = (m>>5)*2048 + (k>>6)*256 + ((k>>3)&7)*32 + (m&31)
//   -> one 32-row group spans 32KB contiguous; GEMM stages region (Gr*2048 +
//      kt*256 + tid) = linear 4KB bursts; wave ks-read = linear lane*16B.

#define MROWS 32768
#define DDIM  512
#define TLEN  4096
#define BSZ   8
#define NCHUNK 64
#define CLEN   64

typedef __attribute__((ext_vector_type(8))) __bf16 bf16x8;
typedef __attribute__((ext_vector_type(16))) float f32x16;

static __device__ __forceinline__ unsigned short f2bf(float f) {
    unsigned int u = __float_as_uint(f);
    u = (u + 0x7FFFu + ((u >> 16) & 1u)) >> 16;   // RNE
    return (unsigned short)u;
}
static __device__ __forceinline__ void gload_lds16(const void* gptr, void* ldsp) {
    __builtin_amdgcn_global_load_lds(
        (const __attribute__((address_space(1))) uint32_t*)gptr,
        (__attribute__((address_space(3))) uint32_t*)ldsp,
        16, 0, 0);
}

#define WAITV(n) asm volatile("s_waitcnt vmcnt(" #n ")" ::: "memory")

// ---------------- cast + permute (X and 6 W) ----------------
// One thread per 16B output slot. Lanes l, l+32 read the two 32B halves of the
// same 64B input line (full line utilization); writes fully coalesced.
__global__ __launch_bounds__(256) void cast_perm(
    const float* __restrict__ x,
    const float* __restrict__ w0, const float* __restrict__ w1,
    const float* __restrict__ w2, const float* __restrict__ w3,
    const float* __restrict__ w4, const float* __restrict__ w5,
    uint4* __restrict__ xp, uint4* __restrict__ wp)
{
    int S = blockIdx.x * 256 + threadIdx.x;      // 0 .. 2293759
    const float* src;
    uint4* dst;
    if (S < 2097152) {                           // X: 1024 groups x 2048 slots
        int Gr = S >> 11, rem = S & 2047;
        int Tk = rem >> 8, c = (rem >> 5) & 7, r = rem & 31;
        src = x + ((size_t)(Gr * 32 + r) * 512 + Tk * 64 + c * 8);
        dst = xp + S;
    } else {                                     // W: 6 gates x 16 groups x 2048
        int SW = S - 2097152;
        int g = SW >> 15, rem2 = SW & 32767;
        int Gn = rem2 >> 11, rem = rem2 & 2047;
        int Tk = rem >> 8, c = (rem >> 5) & 7, r = rem & 31;
        const float* w = (g == 0) ? w0 : (g == 1) ? w1 : (g == 2) ? w2
                       : (g == 3) ? w3 : (g == 4) ? w4 : w5;
        src = w + ((size_t)(Gn * 32 + r) * 512 + Tk * 64 + c * 8);
        dst = wp + SW;
    }
    float4 v0 = *(const float4*)src;
    float4 v1 = *(const float4*)(src + 4);
    uint4 o;
    o.x = (unsigned)f2bf(v0.x) | ((unsigned)f2bf(v0.y) << 16);
    o.y = (unsigned)f2bf(v0.z) | ((unsigned)f2bf(v0.w) << 16);
    o.z = (unsigned)f2bf(v1.x) | ((unsigned)f2bf(v1.y) << 16);
    o.w = (unsigned)f2bf(v1.z) | ((unsigned)f2bf(v1.w) << 16);
    *dst = o;
}

// ---------------- fused gate GEMM + chunk-summary epilogue ----------------
// Identical compute to round 12 (which passed, 0 conflicts): 256 thr / 4 waves
// (2m x 2n), wave 64x32 via 32x32x16 MFMA, BM=128 BN=64 BK=64, ring-2 80KB,
// counted vmcnt(10). Staging sources are now LINEAR reads of the pre-permuted
// Xp/Wp (10 coalesced 4KB bursts); LDS dests unchanged; wave reads linear.
__global__ __launch_bounds__(256, 2) void gates_gemm(
    const unsigned short* __restrict__ X,     // permuted
    const unsigned short* __restrict__ Wf,    // permuted gate bases
    const unsigned short* __restrict__ Wi,
    const unsigned short* __restrict__ Wh,
    const float* __restrict__ bf_, const float* __restrict__ bi_,
    const float* __restrict__ bh_,
    unsigned int* __restrict__ au_out,
    float* __restrict__ Asum, float* __restrict__ Usum)
{
    __shared__ __align__(16) unsigned short lds[2 * 20480];   // 80 KB

    const int tid  = threadIdx.x;
    const int lane = tid & 63;
    const int wave = tid >> 6;                 // 0..3
    const int wm = wave >> 1;                  // 0..1 : 64-row strip (= one chunk)
    const int wn = wave & 1;                   // 0..1 : 32-col strip
    const int ln31 = lane & 31;
    const int kh = lane >> 5;

    // XCD-aware bijective swizzle: 2048 blocks; 8 bx of one by adjacent per XCD.
    const int w = blockIdx.x;
    const int xcd = w & 7;
    const int s = w >> 3;                      // 0..255
    const int by = xcd * 32 + (s >> 3);        // 0..255
    const int bx = s & 7;                      // 0..7
    const int mblk = by * 128;
    const int nblk = bx * 64;

    // staging sources: linear slots (region base + tid), advance 2048 ushorts/tile
    const int grA = mblk >> 5;
    const int gnB = nblk >> 5;
    const unsigned short* gA0 = X  + ((size_t)(grA + 0) * 2048 + tid) * 8;
    const unsigned short* gA1 = X  + ((size_t)(grA + 1) * 2048 + tid) * 8;
    const unsigned short* gA2 = X  + ((size_t)(grA + 2) * 2048 + tid) * 8;
    const unsigned short* gA3 = X  + ((size_t)(grA + 3) * 2048 + tid) * 8;
    const unsigned short* gF0 = Wf + ((size_t)(gnB + 0) * 2048 + tid) * 8;
    const unsigned short* gF1 = Wf + ((size_t)(gnB + 1) * 2048 + tid) * 8;
    const unsigned short* gI0 = Wi + ((size_t)(gnB + 0) * 2048 + tid) * 8;
    const unsigned short* gI1 = Wi + ((size_t)(gnB + 1) * 2048 + tid) * 8;
    const unsigned short* gH0 = Wh + ((size_t)(gnB + 0) * 2048 + tid) * 8;
    const unsigned short* gH1 = Wh + ((size_t)(gnB + 1) * 2048 + tid) * 8;

    const int tid8 = tid * 8;
    const int lane16 = lane * 8;               // linear read vaddr (ushorts)

    f32x16 accF[2], accI[2], accH[2];
#pragma unroll
    for (int mi = 0; mi < 2; ++mi) {
#pragma unroll
        for (int e = 0; e < 16; ++e) { accF[mi][e] = 0.f; accI[mi][e] = 0.f; accH[mi][e] = 0.f; }
    }

#define STAGE(bb) do { \
    gload_lds16(gA0, lds + (bb) + tid8);             \
    gload_lds16(gA1, lds + (bb) + 2048  + tid8);     \
    gload_lds16(gA2, lds + (bb) + 4096  + tid8);     \
    gload_lds16(gA3, lds + (bb) + 6144  + tid8);     \
    gload_lds16(gF0, lds + (bb) + 8192  + tid8);     \
    gload_lds16(gF1, lds + (bb) + 10240 + tid8);     \
    gload_lds16(gI0, lds + (bb) + 12288 + tid8);     \
    gload_lds16(gI1, lds + (bb) + 14336 + tid8);     \
    gload_lds16(gH0, lds + (bb) + 16384 + tid8);     \
    gload_lds16(gH1, lds + (bb) + 18432 + tid8);     \
    gA0 += 2048; gA1 += 2048; gA2 += 2048; gA3 += 2048; gF0 += 2048; \
    gF1 += 2048; gI0 += 2048; gI1 += 2048; gH0 += 2048; gH1 += 2048; } while (0)

    STAGE(0);   // tile 0 -> buf0

#pragma unroll
    for (int t = 0; t < 8; ++t) {
        if (t < 7) {
            STAGE(((t + 1) & 1) * 20480);   // dest protected by t-1's end barrier
            WAITV(10);                       // tile t's 10 loads done; t+1 in flight
        } else {
            WAITV(0);
        }
        __builtin_amdgcn_s_barrier();
        __builtin_amdgcn_sched_barrier(0);

        const unsigned short* cb = lds + (t & 1) * 20480;
#pragma unroll
        for (int ks = 0; ks < 4; ++ks) {
            bf16x8 af0 = *reinterpret_cast<const bf16x8*>(cb + (wm * 8 + ks) * 512 + lane16);
            bf16x8 bF  = *reinterpret_cast<const bf16x8*>(cb + 8192  + (wn * 4 + ks) * 512 + lane16);
            bf16x8 af1 = *reinterpret_cast<const bf16x8*>(cb + (wm * 8 + 4 + ks) * 512 + lane16);
            bf16x8 bI  = *reinterpret_cast<const bf16x8*>(cb + 12288 + (wn * 4 + ks) * 512 + lane16);
            bf16x8 bH  = *reinterpret_cast<const bf16x8*>(cb + 16384 + (wn * 4 + ks) * 512 + lane16);
            __builtin_amdgcn_s_setprio(1);
            accF[0] = __builtin_amdgcn_mfma_f32_32x32x16_bf16(af0, bF, accF[0], 0, 0, 0);
            accF[1] = __builtin_amdgcn_mfma_f32_32x32x16_bf16(af1, bF, accF[1], 0, 0, 0);
            accI[0] = __builtin_amdgcn_mfma_f32_32x32x16_bf16(af0, bI, accI[0], 0, 0, 0);
            accI[1] = __builtin_amdgcn_mfma_f32_32x32x16_bf16(af1, bI, accI[1], 0, 0, 0);
            accH[0] = __builtin_amdgcn_mfma_f32_32x32x16_bf16(af0, bH, accH[0], 0, 0, 0);
            accH[1] = __builtin_amdgcn_mfma_f32_32x32x16_bf16(af1, bH, accH[1], 0, 0, 0);
            __builtin_amdgcn_s_setprio(0);
        }
        __builtin_amdgcn_sched_barrier(0);
        __builtin_amdgcn_s_barrier();   // protects cb from next iteration's STAGE
        __builtin_amdgcn_sched_barrier(0);
    }
#undef STAGE

    // ---- epilogue: gates + packed au + full-chunk summary (same as r12) ----
    const int n = nblk + wn * 32 + ln31;
    const float bfv = bf_[n], biv = bi_[n], bhv = bh_[n];
    const bool up = (lane & 32) != 0;
    float ca = 1.f, cu = 0.f;
#pragma unroll
    for (int mi = 0; mi < 2; ++mi) {
#pragma unroll
        for (int j = 0; j < 4; ++j) {
            float sa = 1.f, su = 0.f;
#pragma unroll
            for (int r = 0; r < 4; ++r) {
                const int reg = 4 * j + r;
                const int m = mblk + wm * 64 + mi * 32 + 8 * j + 4 * kh + r;
                float zf = accF[mi][reg] + bfv;
                float zi = accI[mi][reg] + biv;
                float zh = accH[mi][reg] + bhv;
                float ef = __expf(-zf);
                float ei = __expf(-zi);
                float inv = __frcp_rn(2.0f + ef + ei);
                float av = (1.0f + ei) * inv;
                float uv = (1.0f + ef) * inv * zh;
                au_out[(size_t)m * 512 + n] =
                    ((unsigned int)f2bf(uv) << 16) | (unsigned int)f2bf(av);
                su = av * su + uv; sa *= av;
            }
            float oa = __shfl_xor(sa, 32), ou = __shfl_xor(su, 32);
            float ta = sa * oa;
            float tu = up ? (sa * ou + su) : (oa * su + ou);
            cu = ta * cu + tu; ca = ca * ta;
        }
    }
    if (lane < 32) {
        size_t ci = (size_t)(by * 2 + wm) * 512 + n;
        Asum[ci] = ca;
        Usum[ci] = cu;
    }
}

// ---------------- chunk-prefix (pass2) ----------------
__global__ void scan_pass2(const float4* __restrict__ Asum, const float4* __restrict__ Usum,
                           float4* __restrict__ Hinit) {
    int t = blockIdx.x * 256 + threadIdx.x;  // 0..1023
    int d4 = t & 127;
    int b = t >> 7;
    float4 h = {0.f, 0.f, 0.f, 0.f};
    for (int c = 0; c < NCHUNK; ++c) {
        size_t idx = (size_t)(b * NCHUNK + c) * 128 + d4;
        Hinit[idx] = h;
        float4 A = Asum[idx]; float4 U = Usum[idx];
        h.x = A.x * h.x + U.x; h.y = A.y * h.y + U.y;
        h.z = A.z * h.z + U.z; h.w = A.w * h.w + U.w;
    }
}

// ---------------- pass3 (layer 0): scan -> PERMUTED bf16 h0 ----------------
// Thread owns 8 d (one 16B slot/step). au reads coalesced; permuted 16B writes
// are line-completed by the same thread's next 3 iterations (L2 write-combine).
__global__ void scan_pass3(const uint4* __restrict__ au,
                           const float4* __restrict__ Hinit,
                           uint4* __restrict__ hp) {
    int gid = blockIdx.x * 256 + threadIdx.x;   // 0..32767
    int d8 = gid & 63;
    int c  = (gid >> 6) & 63;
    int b  = gid >> 12;
    const int base_m = b * TLEN + c * CLEN;
    size_t aubase = (size_t)base_m * 128 + d8 * 2;       // uint4 units
    size_t s4 = (size_t)(b * NCHUNK + c) * 128 + d8 * 2;
    float4 h0 = Hinit[s4], h1 = Hinit[s4 + 1];
    float h[8] = {h0.x, h0.y, h0.z, h0.w, h1.x, h1.y, h1.z, h1.w};
    const int Tk = d8 >> 3, cc = d8 & 7;
    for (int l = 0; l < CLEN; ++l) {
        int m = base_m + l;
        uint4 a0 = au[aubase + (size_t)l * 128];
        uint4 a1 = au[aubase + (size_t)l * 128 + 1];
        unsigned vv[8] = {a0.x, a0.y, a0.z, a0.w, a1.x, a1.y, a1.z, a1.w};
        unsigned ob[8];
#pragma unroll
        for (int j = 0; j < 8; ++j) {
            float av = __uint_as_float(vv[j] << 16);
            float uv = __uint_as_float(vv[j] & 0xFFFF0000u);
            h[j] = av * h[j] + uv;
            ob[j] = f2bf(h[j]);
        }
        uint4 o;
        o.x = ob[0] | (ob[1] << 16);
        o.y = ob[2] | (ob[3] << 16);
        o.z = ob[4] | (ob[5] << 16);
        o.w = ob[6] | (ob[7] << 16);
        int S = (m >> 5) * 2048 + Tk * 256 + cc * 32 + (m & 31);
        hp[S] = o;
    }
}

// ---------------- pass3+residual+LN+proj fused (layer 1) ----------------
__global__ __launch_bounds__(128) void scan3_final(
    const uint4* __restrict__ au, const float4* __restrict__ Hinit,
    const float4* __restrict__ x4,
    const float* __restrict__ g, const float* __restrict__ bvec,
    const float* __restrict__ Wout, const float* __restrict__ bout,
    float* __restrict__ out)
{
    const int blk = blockIdx.x;            // 0..511 = b*64 + c
    const int b = blk >> 6, c = blk & 63;
    const int d4 = threadIdx.x;            // 0..127
    const int lane = threadIdx.x & 63;
    const int wv = threadIdx.x >> 6;

    float4 h0 = Hinit[(size_t)blk * 128 + d4];
    float h[4] = {h0.x, h0.y, h0.z, h0.w};
    float4 g4 = reinterpret_cast<const float4*>(g)[d4];
    float4 b4 = reinterpret_cast<const float4*>(bvec)[d4];
    float4 w4 = reinterpret_cast<const float4*>(Wout)[d4];
    const float ga[4] = {g4.x, g4.y, g4.z, g4.w};
    const float ba[4] = {b4.x, b4.y, b4.z, b4.w};
    const float wa[4] = {w4.x, w4.y, w4.z, w4.w};
    const float bo = bout[0];

    __shared__ float redS[2], redQ[2], redP[2];
    size_t base = ((size_t)b * TLEN + c * CLEN) * 128 + d4;

    for (int l = 0; l < CLEN; ++l) {
        size_t idx = base + (size_t)l * 128;
        uint4 v = au[idx];
        float4 xr = x4[idx];
        const unsigned int vv[4] = {v.x, v.y, v.z, v.w};
        const float xa[4] = {xr.x, xr.y, xr.z, xr.w};
        float r[4];
        float sfl = 0.f, q = 0.f;
#pragma unroll
        for (int j = 0; j < 4; ++j) {
            float av = __uint_as_float(vv[j] << 16);
            float uv = __uint_as_float(vv[j] & 0xFFFF0000u);
            h[j] = av * h[j] + uv;
            float hv = h[j];
            if (hv != hv) hv = xa[j];          // NaN fallback
            float rr = xa[j] + hv;
            r[j] = rr;
            sfl += rr; q += rr * rr;
        }
#pragma unroll
        for (int m = 32; m >= 1; m >>= 1) {
            sfl += __shfl_xor(sfl, m);
            q += __shfl_xor(q, m);
        }
        if (lane == 0) { redS[wv] = sfl; redQ[wv] = q; }
        __syncthreads();
        float st = redS[0] + redS[1];
        float qt = redQ[0] + redQ[1];
        float mu = st * (1.0f / 512.0f);
        float var = qt * (1.0f / 512.0f) - mu * mu;
        float rstd = rsqrtf(var + 1e-5f);
        float p = 0.f;
#pragma unroll
        for (int j = 0; j < 4; ++j)
            p += ((r[j] - mu) * rstd * ga[j] + ba[j]) * wa[j];
#pragma unroll
        for (int m = 32; m >= 1; m >>= 1) p += __shfl_xor(p, m);
        if (lane == 0) redP[wv] = p;
        __syncthreads();
        if (threadIdx.x == 0)
            out[(size_t)b * TLEN + c * CLEN + l] = redP[0] + redP[1] + bo;
    }
}

extern "C" void kernel_launch(void* const* d_in, const int* in_sizes, int n_in,
                              void* d_out, int out_size, void* d_ws, size_t ws_size,
                              hipStream_t stream) {
    const float* x    = (const float*)d_in[0];
    const float* Wf0  = (const float*)d_in[1];  const float* bf0 = (const float*)d_in[2];
    const float* Wi0  = (const float*)d_in[3];  const float* bi0 = (const float*)d_in[4];
    const float* Wh0  = (const float*)d_in[5];  const float* bh0 = (const float*)d_in[6];
    const float* Wf1  = (const float*)d_in[7];  const float* bf1 = (const float*)d_in[8];
    const float* Wi1  = (const float*)d_in[9];  const float* bi1 = (const float*)d_in[10];
    const float* Wh1  = (const float*)d_in[11]; const float* bh1 = (const float*)d_in[12];
    const float* ln_g = (const float*)d_in[13]; const float* ln_b = (const float*)d_in[14];
    const float* W_out = (const float*)d_in[15]; const float* b_out = (const float*)d_in[16];

    char* ws = (char*)d_ws;
    unsigned short* Xp = (unsigned short*)ws;  ws += (size_t)MROWS * DDIM * 2;   // 32 MB permuted X
    unsigned short* Wp = (unsigned short*)ws;  ws += (size_t)6 * DDIM * DDIM * 2; // 3 MB permuted W
    unsigned int* aubuf = (unsigned int*)ws;   ws += (size_t)MROWS * DDIM * 4;   // 64 MB packed a|u
    float* Asum = (float*)ws;  ws += (size_t)BSZ * NCHUNK * DDIM * 4;            // 1 MB
    float* Usum = (float*)ws;  ws += (size_t)BSZ * NCHUNK * DDIM * 4;
    float* Hinit = (float*)ws; ws += (size_t)BSZ * NCHUNK * DDIM * 4;
    unsigned short* h0p = (unsigned short*)ws; ws += (size_t)MROWS * DDIM * 2;   // 32 MB permuted h0

    const size_t GSTRIDE = (size_t)DDIM * DDIM;   // ushorts per gate block

    // cast+permute: 2097152 (X) + 196608 (W) slots = 2293760 -> 8960 blocks
    cast_perm<<<8960, 256, 0, stream>>>(
        x, Wf0, Wi0, Wh0, Wf1, Wi1, Wh1, (uint4*)Xp, (uint4*)Wp);

    // ---- layer 0 ----
    gates_gemm<<<2048, 256, 0, stream>>>(Xp, Wp, Wp + GSTRIDE, Wp + 2 * GSTRIDE,
                                         bf0, bi0, bh0, aubuf, Asum, Usum);
    scan_pass2<<<4, 256, 0, stream>>>((const float4*)Asum, (const float4*)Usum, (float4*)Hinit);
    scan_pass3<<<128, 256, 0, stream>>>((const uint4*)aubuf, (const float4*)Hinit, (uint4*)h0p);

    // ---- layer 1 ----
    gates_gemm<<<2048, 256, 0, stream>>>(h0p, Wp + 3 * GSTRIDE, Wp + 4 * GSTRIDE, Wp + 5 * GSTRIDE,
                                         bf1, bi1, bh1, aubuf, Asum, Usum);
    scan_pass2<<<4, 256, 0, stream>>>((const float4*)Asum, (const float4*)Usum, (float4*)Hinit);
    scan3_final<<<512, 128, 0, stream>>>((const uint4*)aubuf, (const float4*)Hinit,
                                         (const float4*)x, ln_g, ln_b, W_out, b_out,
                                         (float*)d_out);
}

// Round 14
// 216.667 us; speedup vs baseline: 1.3031x; 1.1686x over previous
//
#include <hip/hip_runtime.h>
#include <hip/hip_bf16.h>
#include <stdint.h>

// B=8, T=4096, D=512, OUT=1. M = B*T = 32768.
// cast_perm (LDS-transposed, coalesced both sides); fused gates GEMM (r13,
// fragment-major LDS, 0 conflicts, FROZEN); hierarchical pass2; pass3 (permuted
// h0); scan3_final (2-phase LDS).
//
// Permuted layout (16B slots): S = (m>>5)*2048 + (k>>6)*256 + ((k>>3)&7)*32 + (m&31)

#define MROWS 32768
#define DDIM  512
#define TLEN  4096
#define BSZ   8
#define NCHUNK 64
#define CLEN   64

typedef __attribute__((ext_vector_type(8))) __bf16 bf16x8;
typedef __attribute__((ext_vector_type(16))) float f32x16;
typedef __attribute__((ext_vector_type(4))) unsigned short ushort4_t;

static __device__ __forceinline__ unsigned short f2bf(float f) {
    unsigned int u = __float_as_uint(f);
    u = (u + 0x7FFFu + ((u >> 16) & 1u)) >> 16;   // RNE
    return (unsigned short)u;
}
static __device__ __forceinline__ void gload_lds16(const void* gptr, void* ldsp) {
    __builtin_amdgcn_global_load_lds(
        (const __attribute__((address_space(1))) uint32_t*)gptr,
        (__attribute__((address_space(3))) uint32_t*)ldsp,
        16, 0, 0);
}

#define WAITV(n) asm volatile("s_waitcnt vmcnt(" #n ")" ::: "memory")

// ---------------- cast + permute via LDS transpose ----------------
// Block = one 32-row group (32x512). Reads coalesced fp32; LDS bf16 tile with
// row stride 520 ushorts (granule (65r+col)%32 -> conflict-free b128 gathers);
// writes coalesced permuted uint4 slots.
__global__ __launch_bounds__(256) void cast_perm(
    const float* __restrict__ x,
    const float* __restrict__ w0, const float* __restrict__ w1,
    const float* __restrict__ w2, const float* __restrict__ w3,
    const float* __restrict__ w4, const float* __restrict__ w5,
    uint4* __restrict__ xp, uint4* __restrict__ wp)
{
    __shared__ unsigned short t[32 * 520];   // 32.5 KB
    const int blk = blockIdx.x;              // 0..1119
    const int tid = threadIdx.x;
    const float* src;
    uint4* dst;
    if (blk < 1024) {
        src = x + (size_t)blk * 32 * 512;
        dst = xp + (size_t)blk * 2048;
    } else {
        int gb = blk - 1024;                 // 0..95: gate g, group Gn
        int g = gb >> 4;
        const float* w = (g == 0) ? w0 : (g == 1) ? w1 : (g == 2) ? w2
                       : (g == 3) ? w3 : (g == 4) ? w4 : w5;
        src = w + (size_t)(gb & 15) * 32 * 512;
        dst = wp + (size_t)gb * 2048;
    }
#pragma unroll
    for (int p = 0; p < 16; ++p) {
        int idx = p * 256 + tid;             // 0..4095
        int r = idx >> 7, c4 = idx & 127;
        float4 v = reinterpret_cast<const float4*>(src)[(size_t)r * 128 + c4];
        ushort4_t o;
        o.x = f2bf(v.x); o.y = f2bf(v.y); o.z = f2bf(v.z); o.w = f2bf(v.w);
        *reinterpret_cast<ushort4_t*>(&t[r * 520 + c4 * 4]) = o;
    }
    __syncthreads();
#pragma unroll
    for (int q = 0; q < 8; ++q) {
        int s = q * 256 + tid;               // 0..2047
        int Tk = s >> 8, c = (s >> 5) & 7, r = s & 31;
        uint4 o = *reinterpret_cast<const uint4*>(&t[r * 520 + Tk * 64 + c * 8]);
        dst[s] = o;
    }
}

// ---------------- fused gate GEMM + chunk-summary epilogue (r13, frozen) ----
__global__ __launch_bounds__(256, 2) void gates_gemm(
    const unsigned short* __restrict__ X,     // permuted
    const unsigned short* __restrict__ Wf,    // permuted gate bases
    const unsigned short* __restrict__ Wi,
    const unsigned short* __restrict__ Wh,
    const float* __restrict__ bf_, const float* __restrict__ bi_,
    const float* __restrict__ bh_,
    unsigned int* __restrict__ au_out,
    float* __restrict__ Asum, float* __restrict__ Usum)
{
    __shared__ __align__(16) unsigned short lds[2 * 20480];   // 80 KB

    const int tid  = threadIdx.x;
    const int lane = tid & 63;
    const int wave = tid >> 6;                 // 0..3
    const int wm = wave >> 1;                  // 0..1 : 64-row strip (= one chunk)
    const int wn = wave & 1;                   // 0..1 : 32-col strip
    const int ln31 = lane & 31;
    const int kh = lane >> 5;

    const int w = blockIdx.x;
    const int xcd = w & 7;
    const int s = w >> 3;                      // 0..255
    const int by = xcd * 32 + (s >> 3);        // 0..255
    const int bx = s & 7;                      // 0..7
    const int mblk = by * 128;
    const int nblk = bx * 64;

    const int grA = mblk >> 5;
    const int gnB = nblk >> 5;
    const unsigned short* gA0 = X  + ((size_t)(grA + 0) * 2048 + tid) * 8;
    const unsigned short* gA1 = X  + ((size_t)(grA + 1) * 2048 + tid) * 8;
    const unsigned short* gA2 = X  + ((size_t)(grA + 2) * 2048 + tid) * 8;
    const unsigned short* gA3 = X  + ((size_t)(grA + 3) * 2048 + tid) * 8;
    const unsigned short* gF0 = Wf + ((size_t)(gnB + 0) * 2048 + tid) * 8;
    const unsigned short* gF1 = Wf + ((size_t)(gnB + 1) * 2048 + tid) * 8;
    const unsigned short* gI0 = Wi + ((size_t)(gnB + 0) * 2048 + tid) * 8;
    const unsigned short* gI1 = Wi + ((size_t)(gnB + 1) * 2048 + tid) * 8;
    const unsigned short* gH0 = Wh + ((size_t)(gnB + 0) * 2048 + tid) * 8;
    const unsigned short* gH1 = Wh + ((size_t)(gnB + 1) * 2048 + tid) * 8;

    const int tid8 = tid * 8;
    const int lane16 = lane * 8;               // linear read vaddr (ushorts)

    f32x16 accF[2], accI[2], accH[2];
#pragma unroll
    for (int mi = 0; mi < 2; ++mi) {
#pragma unroll
        for (int e = 0; e < 16; ++e) { accF[mi][e] = 0.f; accI[mi][e] = 0.f; accH[mi][e] = 0.f; }
    }

#define STAGE(bb) do { \
    gload_lds16(gA0, lds + (bb) + tid8);             \
    gload_lds16(gA1, lds + (bb) + 2048  + tid8);     \
    gload_lds16(gA2, lds + (bb) + 4096  + tid8);     \
    gload_lds16(gA3, lds + (bb) + 6144  + tid8);     \
    gload_lds16(gF0, lds + (bb) + 8192  + tid8);     \
    gload_lds16(gF1, lds + (bb) + 10240 + tid8);     \
    gload_lds16(gI0, lds + (bb) + 12288 + tid8);     \
    gload_lds16(gI1, lds + (bb) + 14336 + tid8);     \
    gload_lds16(gH0, lds + (bb) + 16384 + tid8);     \
    gload_lds16(gH1, lds + (bb) + 18432 + tid8);     \
    gA0 += 2048; gA1 += 2048; gA2 += 2048; gA3 += 2048; gF0 += 2048; \
    gF1 += 2048; gI0 += 2048; gI1 += 2048; gH0 += 2048; gH1 += 2048; } while (0)

    STAGE(0);   // tile 0 -> buf0

#pragma unroll
    for (int t = 0; t < 8; ++t) {
        if (t < 7) {
            STAGE(((t + 1) & 1) * 20480);   // dest protected by t-1's end barrier
            WAITV(10);                       // tile t's 10 loads done; t+1 in flight
        } else {
            WAITV(0);
        }
        __builtin_amdgcn_s_barrier();
        __builtin_amdgcn_sched_barrier(0);

        const unsigned short* cb = lds + (t & 1) * 20480;
#pragma unroll
        for (int ks = 0; ks < 4; ++ks) {
            bf16x8 af0 = *reinterpret_cast<const bf16x8*>(cb + (wm * 8 + ks) * 512 + lane16);
            bf16x8 bF  = *reinterpret_cast<const bf16x8*>(cb + 8192  + (wn * 4 + ks) * 512 + lane16);
            bf16x8 af1 = *reinterpret_cast<const bf16x8*>(cb + (wm * 8 + 4 + ks) * 512 + lane16);
            bf16x8 bI  = *reinterpret_cast<const bf16x8*>(cb + 12288 + (wn * 4 + ks) * 512 + lane16);
            bf16x8 bH  = *reinterpret_cast<const bf16x8*>(cb + 16384 + (wn * 4 + ks) * 512 + lane16);
            __builtin_amdgcn_s_setprio(1);
            accF[0] = __builtin_amdgcn_mfma_f32_32x32x16_bf16(af0, bF, accF[0], 0, 0, 0);
            accF[1] = __builtin_amdgcn_mfma_f32_32x32x16_bf16(af1, bF, accF[1], 0, 0, 0);
            accI[0] = __builtin_amdgcn_mfma_f32_32x32x16_bf16(af0, bI, accI[0], 0, 0, 0);
            accI[1] = __builtin_amdgcn_mfma_f32_32x32x16_bf16(af1, bI, accI[1], 0, 0, 0);
            accH[0] = __builtin_amdgcn_mfma_f32_32x32x16_bf16(af0, bH, accH[0], 0, 0, 0);
            accH[1] = __builtin_amdgcn_mfma_f32_32x32x16_bf16(af1, bH, accH[1], 0, 0, 0);
            __builtin_amdgcn_s_setprio(0);
        }
        __builtin_amdgcn_sched_barrier(0);
        __builtin_amdgcn_s_barrier();   // protects cb from next iteration's STAGE
        __builtin_amdgcn_sched_barrier(0);
    }
#undef STAGE

    // ---- epilogue: gates + packed au + full-chunk summary ----
    const int n = nblk + wn * 32 + ln31;
    const float bfv = bf_[n], biv = bi_[n], bhv = bh_[n];
    const bool up = (lane & 32) != 0;
    float ca = 1.f, cu = 0.f;
#pragma unroll
    for (int mi = 0; mi < 2; ++mi) {
#pragma unroll
        for (int j = 0; j < 4; ++j) {
            float sa = 1.f, su = 0.f;
#pragma unroll
            for (int r = 0; r < 4; ++r) {
                const int reg = 4 * j + r;
                const int m = mblk + wm * 64 + mi * 32 + 8 * j + 4 * kh + r;
                float zf = accF[mi][reg] + bfv;
                float zi = accI[mi][reg] + biv;
                float zh = accH[mi][reg] + bhv;
                float ef = __expf(-zf);
                float ei = __expf(-zi);
                float inv = __frcp_rn(2.0f + ef + ei);
                float av = (1.0f + ei) * inv;
                float uv = (1.0f + ef) * inv * zh;
                au_out[(size_t)m * 512 + n] =
                    ((unsigned int)f2bf(uv) << 16) | (unsigned int)f2bf(av);
                su = av * su + uv; sa *= av;
            }
            float oa = __shfl_xor(sa, 32), ou = __shfl_xor(su, 32);
            float ta = sa * oa;
            float tu = up ? (sa * ou + su) : (oa * su + ou);
            cu = ta * cu + tu; ca = ca * ta;
        }
    }
    if (lane < 32) {
        size_t ci = (size_t)(by * 2 + wm) * 512 + n;
        Asum[ci] = ca;
        Usum[ci] = cu;
    }
}

// ---------------- chunk-prefix (pass2), hierarchical ----------------
// 8 threads per (b,d4) column: 8 serial composes + 3-step shfl scan + 8 writes.
__global__ __launch_bounds__(256) void scan_pass2(
    const float4* __restrict__ Asum, const float4* __restrict__ Usum,
    float4* __restrict__ Hinit)
{
    int gid = blockIdx.x * 256 + threadIdx.x;   // 0..8191
    int col = gid >> 3;                          // 0..1023 = b*128 + d4
    int t8  = gid & 7;
    int b = col >> 7, d4 = col & 127;
    int lane = threadIdx.x & 63;

    float4 a[8], u[8];
    float4 Ac = {1.f, 1.f, 1.f, 1.f}, Uc = {0.f, 0.f, 0.f, 0.f};
#pragma unroll
    for (int j = 0; j < 8; ++j) {
        size_t idx = (size_t)(b * 64 + t8 * 8 + j) * 128 + d4;
        a[j] = Asum[idx]; u[j] = Usum[idx];
        Uc.x = a[j].x * Uc.x + u[j].x; Uc.y = a[j].y * Uc.y + u[j].y;
        Uc.z = a[j].z * Uc.z + u[j].z; Uc.w = a[j].w * Uc.w + u[j].w;
        Ac.x *= a[j].x; Ac.y *= a[j].y; Ac.z *= a[j].z; Ac.w *= a[j].w;
    }
    // inclusive scan over t8 (compose other-before-self)
#pragma unroll
    for (int d = 1; d < 8; d <<= 1) {
        float4 Ao, Uo;
        Ao.x = __shfl(Ac.x, lane - d); Ao.y = __shfl(Ac.y, lane - d);
        Ao.z = __shfl(Ac.z, lane - d); Ao.w = __shfl(Ac.w, lane - d);
        Uo.x = __shfl(Uc.x, lane - d); Uo.y = __shfl(Uc.y, lane - d);
        Uo.z = __shfl(Uc.z, lane - d); Uo.w = __shfl(Uc.w, lane - d);
        if (t8 >= d) {
            Uc.x = Ac.x * Uo.x + Uc.x; Uc.y = Ac.y * Uo.y + Uc.y;
            Uc.z = Ac.z * Uo.z + Uc.z; Uc.w = Ac.w * Uo.w + Uc.w;
            Ac.x *= Ao.x; Ac.y *= Ao.y; Ac.z *= Ao.z; Ac.w *= Ao.w;
        }
    }
    // exclusive prefix -> starting h
    float4 h;
    h.x = __shfl(Uc.x, lane - 1); h.y = __shfl(Uc.y, lane - 1);
    h.z = __shfl(Uc.z, lane - 1); h.w = __shfl(Uc.w, lane - 1);
    if (t8 == 0) { h.x = 0.f; h.y = 0.f; h.z = 0.f; h.w = 0.f; }
#pragma unroll
    for (int j = 0; j < 8; ++j) {
        size_t idx = (size_t)(b * 64 + t8 * 8 + j) * 128 + d4;
        Hinit[idx] = h;
        h.x = a[j].x * h.x + u[j].x; h.y = a[j].y * h.y + u[j].y;
        h.z = a[j].z * h.z + u[j].z; h.w = a[j].w * h.w + u[j].w;
    }
}

// ---------------- pass3 (layer 0): scan -> PERMUTED bf16 h0 ----------------
__global__ void scan_pass3(const uint4* __restrict__ au,
                           const float4* __restrict__ Hinit,
                           uint4* __restrict__ hp) {
    int gid = blockIdx.x * 256 + threadIdx.x;   // 0..32767
    int d8 = gid & 63;
    int c  = (gid >> 6) & 63;
    int b  = gid >> 12;
    const int base_m = b * TLEN + c * CLEN;
    size_t aubase = (size_t)base_m * 128 + d8 * 2;       // uint4 units
    size_t s4 = (size_t)(b * NCHUNK + c) * 128 + d8 * 2;
    float4 h0 = Hinit[s4], h1 = Hinit[s4 + 1];
    float h[8] = {h0.x, h0.y, h0.z, h0.w, h1.x, h1.y, h1.z, h1.w};
    const int Tk = d8 >> 3, cc = d8 & 7;
    for (int l = 0; l < CLEN; ++l) {
        int m = base_m + l;
        uint4 a0 = au[aubase + (size_t)l * 128];
        uint4 a1 = au[aubase + (size_t)l * 128 + 1];
        unsigned vv[8] = {a0.x, a0.y, a0.z, a0.w, a1.x, a1.y, a1.z, a1.w};
        unsigned ob[8];
#pragma unroll
        for (int j = 0; j < 8; ++j) {
            float av = __uint_as_float(vv[j] << 16);
            float uv = __uint_as_float(vv[j] & 0xFFFF0000u);
            h[j] = av * h[j] + uv;
            ob[j] = f2bf(h[j]);
        }
        uint4 o;
        o.x = ob[0] | (ob[1] << 16);
        o.y = ob[2] | (ob[3] << 16);
        o.z = ob[4] | (ob[5] << 16);
        o.w = ob[6] | (ob[7] << 16);
        int S = (m >> 5) * 2048 + Tk * 256 + cc * 32 + (m & 31);
        hp[S] = o;
    }
}

// ---------------- pass3+residual+LN+proj fused (layer 1), 2-phase ----------
// Phase 1: per-thread scan writes bf16 residuals to LDS[64][512] (1 barrier).
// Phase 2: wave-parallel rows -- each wave reduces 32 rows via shfl butterflies.
__global__ __launch_bounds__(128) void scan3_final(
    const uint4* __restrict__ au, const float4* __restrict__ Hinit,
    const float4* __restrict__ x4,
    const float* __restrict__ g, const float* __restrict__ bvec,
    const float* __restrict__ Wout, const float* __restrict__ bout,
    float* __restrict__ out)
{
    __shared__ unsigned short rl[64 * 512];    // 64 KB bf16 residuals
    const int blk = blockIdx.x;                // 0..511 = b*64 + c
    const int b = blk >> 6, c = blk & 63;
    const int d4 = threadIdx.x;                // 0..127

    float4 h0 = Hinit[(size_t)blk * 128 + d4];
    float h[4] = {h0.x, h0.y, h0.z, h0.w};
    size_t base = ((size_t)b * TLEN + c * CLEN) * 128 + d4;

#pragma unroll 4
    for (int l = 0; l < CLEN; ++l) {
        size_t idx = base + (size_t)l * 128;
        uint4 v = au[idx];
        float4 xr = x4[idx];
        const unsigned vv[4] = {v.x, v.y, v.z, v.w};
        const float xa[4] = {xr.x, xr.y, xr.z, xr.w};
        ushort4_t o;
#pragma unroll
        for (int j = 0; j < 4; ++j) {
            float av = __uint_as_float(vv[j] << 16);
            float uv = __uint_as_float(vv[j] & 0xFFFF0000u);
            h[j] = av * h[j] + uv;
            float hv = h[j];
            if (hv != hv) hv = xa[j];          // NaN fallback
            o[j] = f2bf(xa[j] + hv);
        }
        *reinterpret_cast<ushort4_t*>(&rl[l * 512 + d4 * 4]) = o;
    }
    __syncthreads();

    const int lane = threadIdx.x & 63;
    const int wv = threadIdx.x >> 6;
    float4 g0 = reinterpret_cast<const float4*>(g)[lane * 2];
    float4 g1 = reinterpret_cast<const float4*>(g)[lane * 2 + 1];
    float4 b0 = reinterpret_cast<const float4*>(bvec)[lane * 2];
    float4 b1 = reinterpret_cast<const float4*>(bvec)[lane * 2 + 1];
    float4 w0 = reinterpret_cast<const float4*>(Wout)[lane * 2];
    float4 w1 = reinterpret_cast<const float4*>(Wout)[lane * 2 + 1];
    const float gg[8] = {g0.x, g0.y, g0.z, g0.w, g1.x, g1.y, g1.z, g1.w};
    const float bb[8] = {b0.x, b0.y, b0.z, b0.w, b1.x, b1.y, b1.z, b1.w};
    const float ww[8] = {w0.x, w0.y, w0.z, w0.w, w1.x, w1.y, w1.z, w1.w};
    const float bo = bout[0];

    for (int rr = 0; rr < 32; ++rr) {
        const int row = wv * 32 + rr;
        uint4 rv = *reinterpret_cast<const uint4*>(&rl[row * 512 + lane * 8]);
        const unsigned rw[4] = {rv.x, rv.y, rv.z, rv.w};
        float r[8];
#pragma unroll
        for (int j = 0; j < 4; ++j) {
            r[2 * j]     = __uint_as_float(rw[j] << 16);
            r[2 * j + 1] = __uint_as_float(rw[j] & 0xFFFF0000u);
        }
        float s = 0.f, q = 0.f;
#pragma unroll
        for (int j = 0; j < 8; ++j) { s += r[j]; q += r[j] * r[j]; }
#pragma unroll
        for (int m = 32; m >= 1; m >>= 1) {
            s += __shfl_xor(s, m);
            q += __shfl_xor(q, m);
        }
        float mu = s * (1.0f / 512.0f);
        float var = q * (1.0f / 512.0f) - mu * mu;
        float rstd = rsqrtf(var + 1e-5f);
        float p = 0.f;
#pragma unroll
        for (int j = 0; j < 8; ++j)
            p += ((r[j] - mu) * rstd * gg[j] + bb[j]) * ww[j];
#pragma unroll
        for (int m = 32; m >= 1; m >>= 1) p += __shfl_xor(p, m);
        if (lane == 0)
            out[(size_t)b * TLEN + c * CLEN + row] = p + bo;
    }
}

extern "C" void kernel_launch(void* const* d_in, const int* in_sizes, int n_in,
                              void* d_out, int out_size, void* d_ws, size_t ws_size,
                              hipStream_t stream) {
    const float* x    = (const float*)d_in[0];
    const float* Wf0  = (const float*)d_in[1];  const float* bf0 = (const float*)d_in[2];
    const float* Wi0  = (const float*)d_in[3];  const float* bi0 = (const float*)d_in[4];
    const float* Wh0  = (const float*)d_in[5];  const float* bh0 = (const float*)d_in[6];
    const float* Wf1  = (const float*)d_in[7];  const float* bf1 = (const float*)d_in[8];
    const float* Wi1  = (const float*)d_in[9];  const float* bi1 = (const float*)d_in[10];
    const float* Wh1  = (const float*)d_in[11]; const float* bh1 = (const float*)d_in[12];
    const float* ln_g = (const float*)d_in[13]; const float* ln_b = (const float*)d_in[14];
    const float* W_out = (const float*)d_in[15]; const float* b_out = (const float*)d_in[16];

    char* ws = (char*)d_ws;
    unsigned short* Xp = (unsigned short*)ws;  ws += (size_t)MROWS * DDIM * 2;   // 32 MB permuted X
    unsigned short* Wp = (unsigned short*)ws;  ws += (size_t)6 * DDIM * DDIM * 2; // 3 MB permuted W
    unsigned int* aubuf = (unsigned int*)ws;   ws += (size_t)MROWS * DDIM * 4;   // 64 MB packed a|u
    float* Asum = (float*)ws;  ws += (size_t)BSZ * NCHUNK * DDIM * 4;            // 1 MB
    float* Usum = (float*)ws;  ws += (size_t)BSZ * NCHUNK * DDIM * 4;
    float* Hinit = (float*)ws; ws += (size_t)BSZ * NCHUNK * DDIM * 4;
    unsigned short* h0p = (unsigned short*)ws; ws += (size_t)MROWS * DDIM * 2;   // 32 MB permuted h0

    const size_t GSTRIDE = (size_t)DDIM * DDIM;   // ushorts per gate block

    // cast+permute: 1024 X groups + 96 W groups
    cast_perm<<<1120, 256, 0, stream>>>(
        x, Wf0, Wi0, Wh0, Wf1, Wi1, Wh1, (uint4*)Xp, (uint4*)Wp);

    // ---- layer 0 ----
    gates_gemm<<<2048, 256, 0, stream>>>(Xp, Wp, Wp + GSTRIDE, Wp + 2 * GSTRIDE,
                                         bf0, bi0, bh0, aubuf, Asum, Usum);
    scan_pass2<<<32, 256, 0, stream>>>((const float4*)Asum, (const float4*)Usum, (float4*)Hinit);
    scan_pass3<<<128, 256, 0, stream>>>((const uint4*)aubuf, (const float4*)Hinit, (uint4*)h0p);

    // ---- layer 1 ----
    gates_gemm<<<2048, 256, 0, stream>>>(h0p, Wp + 3 * GSTRIDE, Wp + 4 * GSTRIDE, Wp + 5 * GSTRIDE,
                                         bf1, bi1, bh1, aubuf, Asum, Usum);
    scan_pass2<<<32, 256, 0, stream>>>((const float4*)Asum, (const float4*)Usum, (float4*)Hinit);
    scan3_final<<<512, 128, 0, stream>>>((const uint4*)aubuf, (const float4*)Hinit,
                                         (const float4*)x, ln_g, ln_b, W_out, b_out,
                                         (float*)d_out);
}

// Round 15
// 208.049 us; speedup vs baseline: 1.3570x; 1.0414x over previous
//
#include <hip/hip_runtime.h>
#include <hip/hip_bf16.h>
#include <stdint.h>

// B=8, T=4096, D=512, OUT=1. M = B*T = 32768.
// cast_perm (LDS-transposed, coalesced both sides); fused gates GEMM (r13,
// fragment-major LDS, 0 conflicts, FROZEN); hierarchical pass2; pass3 (permuted
// h0); scan3_final (2-phase LDS, 256 thr).
//
// Permuted layout (16B slots): S = (m>>5)*2048 + (k>>6)*256 + ((k>>3)&7)*32 + (m&31)

#define MROWS 32768
#define DDIM  512
#define TLEN  4096
#define BSZ   8
#define NCHUNK 64
#define CLEN   64

typedef __attribute__((ext_vector_type(8))) __bf16 bf16x8;
typedef __attribute__((ext_vector_type(16))) float f32x16;
typedef __attribute__((ext_vector_type(4))) unsigned short ushort4_t;
typedef __attribute__((ext_vector_type(2))) unsigned short ushort2_t;

static __device__ __forceinline__ unsigned short f2bf(float f) {
    unsigned int u = __float_as_uint(f);
    u = (u + 0x7FFFu + ((u >> 16) & 1u)) >> 16;   // RNE
    return (unsigned short)u;
}
static __device__ __forceinline__ void gload_lds16(const void* gptr, void* ldsp) {
    __builtin_amdgcn_global_load_lds(
        (const __attribute__((address_space(1))) uint32_t*)gptr,
        (__attribute__((address_space(3))) uint32_t*)ldsp,
        16, 0, 0);
}

#define WAITV(n) asm volatile("s_waitcnt vmcnt(" #n ")" ::: "memory")

// ---------------- cast + permute via LDS transpose ----------------
__global__ __launch_bounds__(256) void cast_perm(
    const float* __restrict__ x,
    const float* __restrict__ w0, const float* __restrict__ w1,
    const float* __restrict__ w2, const float* __restrict__ w3,
    const float* __restrict__ w4, const float* __restrict__ w5,
    uint4* __restrict__ xp, uint4* __restrict__ wp)
{
    __shared__ unsigned short t[32 * 520];   // 32.5 KB
    const int blk = blockIdx.x;              // 0..1119
    const int tid = threadIdx.x;
    const float* src;
    uint4* dst;
    if (blk < 1024) {
        src = x + (size_t)blk * 32 * 512;
        dst = xp + (size_t)blk * 2048;
    } else {
        int gb = blk - 1024;                 // 0..95: gate g, group Gn
        int g = gb >> 4;
        const float* w = (g == 0) ? w0 : (g == 1) ? w1 : (g == 2) ? w2
                       : (g == 3) ? w3 : (g == 4) ? w4 : w5;
        src = w + (size_t)(gb & 15) * 32 * 512;
        dst = wp + (size_t)gb * 2048;
    }
#pragma unroll
    for (int p = 0; p < 16; ++p) {
        int idx = p * 256 + tid;             // 0..4095
        int r = idx >> 7, c4 = idx & 127;
        float4 v = reinterpret_cast<const float4*>(src)[(size_t)r * 128 + c4];
        ushort4_t o;
        o.x = f2bf(v.x); o.y = f2bf(v.y); o.z = f2bf(v.z); o.w = f2bf(v.w);
        *reinterpret_cast<ushort4_t*>(&t[r * 520 + c4 * 4]) = o;
    }
    __syncthreads();
#pragma unroll
    for (int q = 0; q < 8; ++q) {
        int s = q * 256 + tid;               // 0..2047
        int Tk = s >> 8, c = (s >> 5) & 7, r = s & 31;
        uint4 o = *reinterpret_cast<const uint4*>(&t[r * 520 + Tk * 64 + c * 8]);
        dst[s] = o;
    }
}

// ---------------- fused gate GEMM + chunk-summary epilogue (frozen) ----------
__global__ __launch_bounds__(256, 2) void gates_gemm(
    const unsigned short* __restrict__ X,     // permuted
    const unsigned short* __restrict__ Wf,    // permuted gate bases
    const unsigned short* __restrict__ Wi,
    const unsigned short* __restrict__ Wh,
    const float* __restrict__ bf_, const float* __restrict__ bi_,
    const float* __restrict__ bh_,
    unsigned int* __restrict__ au_out,
    float* __restrict__ Asum, float* __restrict__ Usum)
{
    __shared__ __align__(16) unsigned short lds[2 * 20480];   // 80 KB

    const int tid  = threadIdx.x;
    const int lane = tid & 63;
    const int wave = tid >> 6;                 // 0..3
    const int wm = wave >> 1;                  // 0..1 : 64-row strip (= one chunk)
    const int wn = wave & 1;                   // 0..1 : 32-col strip
    const int ln31 = lane & 31;
    const int kh = lane >> 5;

    const int w = blockIdx.x;
    const int xcd = w & 7;
    const int s = w >> 3;                      // 0..255
    const int by = xcd * 32 + (s >> 3);        // 0..255
    const int bx = s & 7;                      // 0..7
    const int mblk = by * 128;
    const int nblk = bx * 64;

    const int grA = mblk >> 5;
    const int gnB = nblk >> 5;
    const unsigned short* gA0 = X  + ((size_t)(grA + 0) * 2048 + tid) * 8;
    const unsigned short* gA1 = X  + ((size_t)(grA + 1) * 2048 + tid) * 8;
    const unsigned short* gA2 = X  + ((size_t)(grA + 2) * 2048 + tid) * 8;
    const unsigned short* gA3 = X  + ((size_t)(grA + 3) * 2048 + tid) * 8;
    const unsigned short* gF0 = Wf + ((size_t)(gnB + 0) * 2048 + tid) * 8;
    const unsigned short* gF1 = Wf + ((size_t)(gnB + 1) * 2048 + tid) * 8;
    const unsigned short* gI0 = Wi + ((size_t)(gnB + 0) * 2048 + tid) * 8;
    const unsigned short* gI1 = Wi + ((size_t)(gnB + 1) * 2048 + tid) * 8;
    const unsigned short* gH0 = Wh + ((size_t)(gnB + 0) * 2048 + tid) * 8;
    const unsigned short* gH1 = Wh + ((size_t)(gnB + 1) * 2048 + tid) * 8;

    const int tid8 = tid * 8;
    const int lane16 = lane * 8;               // linear read vaddr (ushorts)

    f32x16 accF[2], accI[2], accH[2];
#pragma unroll
    for (int mi = 0; mi < 2; ++mi) {
#pragma unroll
        for (int e = 0; e < 16; ++e) { accF[mi][e] = 0.f; accI[mi][e] = 0.f; accH[mi][e] = 0.f; }
    }

#define STAGE(bb) do { \
    gload_lds16(gA0, lds + (bb) + tid8);             \
    gload_lds16(gA1, lds + (bb) + 2048  + tid8);     \
    gload_lds16(gA2, lds + (bb) + 4096  + tid8);     \
    gload_lds16(gA3, lds + (bb) + 6144  + tid8);     \
    gload_lds16(gF0, lds + (bb) + 8192  + tid8);     \
    gload_lds16(gF1, lds + (bb) + 10240 + tid8);     \
    gload_lds16(gI0, lds + (bb) + 12288 + tid8);     \
    gload_lds16(gI1, lds + (bb) + 14336 + tid8);     \
    gload_lds16(gH0, lds + (bb) + 16384 + tid8);     \
    gload_lds16(gH1, lds + (bb) + 18432 + tid8);     \
    gA0 += 2048; gA1 += 2048; gA2 += 2048; gA3 += 2048; gF0 += 2048; \
    gF1 += 2048; gI0 += 2048; gI1 += 2048; gH0 += 2048; gH1 += 2048; } while (0)

    STAGE(0);   // tile 0 -> buf0

#pragma unroll
    for (int t = 0; t < 8; ++t) {
        if (t < 7) {
            STAGE(((t + 1) & 1) * 20480);   // dest protected by t-1's end barrier
            WAITV(10);                       // tile t's 10 loads done; t+1 in flight
        } else {
            WAITV(0);
        }
        __builtin_amdgcn_s_barrier();
        __builtin_amdgcn_sched_barrier(0);

        const unsigned short* cb = lds + (t & 1) * 20480;
#pragma unroll
        for (int ks = 0; ks < 4; ++ks) {
            bf16x8 af0 = *reinterpret_cast<const bf16x8*>(cb + (wm * 8 + ks) * 512 + lane16);
            bf16x8 bF  = *reinterpret_cast<const bf16x8*>(cb + 8192  + (wn * 4 + ks) * 512 + lane16);
            bf16x8 af1 = *reinterpret_cast<const bf16x8*>(cb + (wm * 8 + 4 + ks) * 512 + lane16);
            bf16x8 bI  = *reinterpret_cast<const bf16x8*>(cb + 12288 + (wn * 4 + ks) * 512 + lane16);
            bf16x8 bH  = *reinterpret_cast<const bf16x8*>(cb + 16384 + (wn * 4 + ks) * 512 + lane16);
            __builtin_amdgcn_s_setprio(1);
            accF[0] = __builtin_amdgcn_mfma_f32_32x32x16_bf16(af0, bF, accF[0], 0, 0, 0);
            accF[1] = __builtin_amdgcn_mfma_f32_32x32x16_bf16(af1, bF, accF[1], 0, 0, 0);
            accI[0] = __builtin_amdgcn_mfma_f32_32x32x16_bf16(af0, bI, accI[0], 0, 0, 0);
            accI[1] = __builtin_amdgcn_mfma_f32_32x32x16_bf16(af1, bI, accI[1], 0, 0, 0);
            accH[0] = __builtin_amdgcn_mfma_f32_32x32x16_bf16(af0, bH, accH[0], 0, 0, 0);
            accH[1] = __builtin_amdgcn_mfma_f32_32x32x16_bf16(af1, bH, accH[1], 0, 0, 0);
            __builtin_amdgcn_s_setprio(0);
        }
        __builtin_amdgcn_sched_barrier(0);
        __builtin_amdgcn_s_barrier();   // protects cb from next iteration's STAGE
        __builtin_amdgcn_sched_barrier(0);
    }
#undef STAGE

    // ---- epilogue: gates + packed au + full-chunk summary ----
    const int n = nblk + wn * 32 + ln31;
    const float bfv = bf_[n], biv = bi_[n], bhv = bh_[n];
    const bool up = (lane & 32) != 0;
    float ca = 1.f, cu = 0.f;
#pragma unroll
    for (int mi = 0; mi < 2; ++mi) {
#pragma unroll
        for (int j = 0; j < 4; ++j) {
            float sa = 1.f, su = 0.f;
#pragma unroll
            for (int r = 0; r < 4; ++r) {
                const int reg = 4 * j + r;
                const int m = mblk + wm * 64 + mi * 32 + 8 * j + 4 * kh + r;
                float zf = accF[mi][reg] + bfv;
                float zi = accI[mi][reg] + biv;
                float zh = accH[mi][reg] + bhv;
                float ef = __expf(-zf);
                float ei = __expf(-zi);
                float inv = __frcp_rn(2.0f + ef + ei);
                float av = (1.0f + ei) * inv;
                float uv = (1.0f + ef) * inv * zh;
                au_out[(size_t)m * 512 + n] =
                    ((unsigned int)f2bf(uv) << 16) | (unsigned int)f2bf(av);
                su = av * su + uv; sa *= av;
            }
            float oa = __shfl_xor(sa, 32), ou = __shfl_xor(su, 32);
            float ta = sa * oa;
            float tu = up ? (sa * ou + su) : (oa * su + ou);
            cu = ta * cu + tu; ca = ca * ta;
        }
    }
    if (lane < 32) {
        size_t ci = (size_t)(by * 2 + wm) * 512 + n;
        Asum[ci] = ca;
        Usum[ci] = cu;
    }
}

// ---------------- chunk-prefix (pass2), hierarchical ----------------
__global__ __launch_bounds__(256) void scan_pass2(
    const float4* __restrict__ Asum, const float4* __restrict__ Usum,
    float4* __restrict__ Hinit)
{
    int gid = blockIdx.x * 256 + threadIdx.x;   // 0..8191
    int col = gid >> 3;                          // 0..1023 = b*128 + d4
    int t8  = gid & 7;
    int b = col >> 7, d4 = col & 127;
    int lane = threadIdx.x & 63;

    float4 a[8], u[8];
    float4 Ac = {1.f, 1.f, 1.f, 1.f}, Uc = {0.f, 0.f, 0.f, 0.f};
#pragma unroll
    for (int j = 0; j < 8; ++j) {
        size_t idx = (size_t)(b * 64 + t8 * 8 + j) * 128 + d4;
        a[j] = Asum[idx]; u[j] = Usum[idx];
        Uc.x = a[j].x * Uc.x + u[j].x; Uc.y = a[j].y * Uc.y + u[j].y;
        Uc.z = a[j].z * Uc.z + u[j].z; Uc.w = a[j].w * Uc.w + u[j].w;
        Ac.x *= a[j].x; Ac.y *= a[j].y; Ac.z *= a[j].z; Ac.w *= a[j].w;
    }
#pragma unroll
    for (int d = 1; d < 8; d <<= 1) {
        float4 Ao, Uo;
        Ao.x = __shfl(Ac.x, lane - d); Ao.y = __shfl(Ac.y, lane - d);
        Ao.z = __shfl(Ac.z, lane - d); Ao.w = __shfl(Ac.w, lane - d);
        Uo.x = __shfl(Uc.x, lane - d); Uo.y = __shfl(Uc.y, lane - d);
        Uo.z = __shfl(Uc.z, lane - d); Uo.w = __shfl(Uc.w, lane - d);
        if (t8 >= d) {
            Uc.x = Ac.x * Uo.x + Uc.x; Uc.y = Ac.y * Uo.y + Uc.y;
            Uc.z = Ac.z * Uo.z + Uc.z; Uc.w = Ac.w * Uo.w + Uc.w;
            Ac.x *= Ao.x; Ac.y *= Ao.y; Ac.z *= Ao.z; Ac.w *= Ao.w;
        }
    }
    float4 h;
    h.x = __shfl(Uc.x, lane - 1); h.y = __shfl(Uc.y, lane - 1);
    h.z = __shfl(Uc.z, lane - 1); h.w = __shfl(Uc.w, lane - 1);
    if (t8 == 0) { h.x = 0.f; h.y = 0.f; h.z = 0.f; h.w = 0.f; }
#pragma unroll
    for (int j = 0; j < 8; ++j) {
        size_t idx = (size_t)(b * 64 + t8 * 8 + j) * 128 + d4;
        Hinit[idx] = h;
        h.x = a[j].x * h.x + u[j].x; h.y = a[j].y * h.y + u[j].y;
        h.z = a[j].z * h.z + u[j].z; h.w = a[j].w * h.w + u[j].w;
    }
}

// ---------------- pass3 (layer 0): scan -> PERMUTED bf16 h0 ----------------
__global__ void scan_pass3(const uint4* __restrict__ au,
                           const float4* __restrict__ Hinit,
                           uint4* __restrict__ hp) {
    int gid = blockIdx.x * 256 + threadIdx.x;   // 0..32767
    int d8 = gid & 63;
    int c  = (gid >> 6) & 63;
    int b  = gid >> 12;
    const int base_m = b * TLEN + c * CLEN;
    size_t aubase = (size_t)base_m * 128 + d8 * 2;       // uint4 units
    size_t s4 = (size_t)(b * NCHUNK + c) * 128 + d8 * 2;
    float4 h0 = Hinit[s4], h1 = Hinit[s4 + 1];
    float h[8] = {h0.x, h0.y, h0.z, h0.w, h1.x, h1.y, h1.z, h1.w};
    const int Tk = d8 >> 3, cc = d8 & 7;
    for (int l = 0; l < CLEN; ++l) {
        int m = base_m + l;
        uint4 a0 = au[aubase + (size_t)l * 128];
        uint4 a1 = au[aubase + (size_t)l * 128 + 1];
        unsigned vv[8] = {a0.x, a0.y, a0.z, a0.w, a1.x, a1.y, a1.z, a1.w};
        unsigned ob[8];
#pragma unroll
        for (int j = 0; j < 8; ++j) {
            float av = __uint_as_float(vv[j] << 16);
            float uv = __uint_as_float(vv[j] & 0xFFFF0000u);
            h[j] = av * h[j] + uv;
            ob[j] = f2bf(h[j]);
        }
        uint4 o;
        o.x = ob[0] | (ob[1] << 16);
        o.y = ob[2] | (ob[3] << 16);
        o.z = ob[4] | (ob[5] << 16);
        o.w = ob[6] | (ob[7] << 16);
        int S = (m >> 5) * 2048 + Tk * 256 + cc * 32 + (m & 31);
        hp[S] = o;
    }
}

// ---------------- pass3+residual+LN+proj fused (layer 1), 2-phase 256thr ----
// Phase 1: 256 thr, d2-granularity scan -> bf16 residuals in LDS[64][512]
// (1 barrier). Phase 2: 4 waves x 16 rows, shfl-butterfly LN + projection.
__global__ __launch_bounds__(256) void scan3_final(
    const uint2* __restrict__ au2, const float2* __restrict__ Hinit2,
    const float2* __restrict__ x2,
    const float* __restrict__ g, const float* __restrict__ bvec,
    const float* __restrict__ Wout, const float* __restrict__ bout,
    float* __restrict__ out)
{
    __shared__ unsigned short rl[64 * 512];    // 64 KB bf16 residuals
    const int blk = blockIdx.x;                // 0..511 = b*64 + c
    const int b = blk >> 6, c = blk & 63;
    const int d2 = threadIdx.x;                // 0..255 (2 d's each)

    float2 h0 = Hinit2[(size_t)blk * 256 + d2];
    float h[2] = {h0.x, h0.y};
    size_t base = ((size_t)b * TLEN + c * CLEN) * 256 + d2;

#pragma unroll 4
    for (int l = 0; l < CLEN; ++l) {
        size_t idx = base + (size_t)l * 256;
        uint2 v = au2[idx];
        float2 xr = x2[idx];
        const unsigned vv[2] = {v.x, v.y};
        const float xa[2] = {xr.x, xr.y};
        ushort2_t o;
#pragma unroll
        for (int j = 0; j < 2; ++j) {
            float av = __uint_as_float(vv[j] << 16);
            float uv = __uint_as_float(vv[j] & 0xFFFF0000u);
            h[j] = av * h[j] + uv;
            float hv = h[j];
            if (hv != hv) hv = xa[j];          // NaN fallback
            o[j] = f2bf(xa[j] + hv);
        }
        *reinterpret_cast<ushort2_t*>(&rl[l * 512 + d2 * 2]) = o;
    }
    __syncthreads();

    const int lane = threadIdx.x & 63;
    const int wv = threadIdx.x >> 6;           // 0..3
    float4 g0 = reinterpret_cast<const float4*>(g)[lane * 2];
    float4 g1 = reinterpret_cast<const float4*>(g)[lane * 2 + 1];
    float4 b0 = reinterpret_cast<const float4*>(bvec)[lane * 2];
    float4 b1 = reinterpret_cast<const float4*>(bvec)[lane * 2 + 1];
    float4 w0 = reinterpret_cast<const float4*>(Wout)[lane * 2];
    float4 w1 = reinterpret_cast<const float4*>(Wout)[lane * 2 + 1];
    const float gg[8] = {g0.x, g0.y, g0.z, g0.w, g1.x, g1.y, g1.z, g1.w};
    const float bb[8] = {b0.x, b0.y, b0.z, b0.w, b1.x, b1.y, b1.z, b1.w};
    const float ww[8] = {w0.x, w0.y, w0.z, w0.w, w1.x, w1.y, w1.z, w1.w};
    const float bo = bout[0];

    for (int rr = 0; rr < 16; ++rr) {
        const int row = wv * 16 + rr;
        uint4 rv = *reinterpret_cast<const uint4*>(&rl[row * 512 + lane * 8]);
        const unsigned rw[4] = {rv.x, rv.y, rv.z, rv.w};
        float r[8];
#pragma unroll
        for (int j = 0; j < 4; ++j) {
            r[2 * j]     = __uint_as_float(rw[j] << 16);
            r[2 * j + 1] = __uint_as_float(rw[j] & 0xFFFF0000u);
        }
        float s = 0.f, q = 0.f;
#pragma unroll
        for (int j = 0; j < 8; ++j) { s += r[j]; q += r[j] * r[j]; }
#pragma unroll
        for (int m = 32; m >= 1; m >>= 1) {
            s += __shfl_xor(s, m);
            q += __shfl_xor(q, m);
        }
        float mu = s * (1.0f / 512.0f);
        float var = q * (1.0f / 512.0f) - mu * mu;
        float rstd = rsqrtf(var + 1e-5f);
        float p = 0.f;
#pragma unroll
        for (int j = 0; j < 8; ++j)
            p += ((r[j] - mu) * rstd * gg[j] + bb[j]) * ww[j];
#pragma unroll
        for (int m = 32; m >= 1; m >>= 1) p += __shfl_xor(p, m);
        if (lane == 0)
            out[(size_t)b * TLEN + c * CLEN + row] = p + bo;
    }
}

extern "C" void kernel_launch(void* const* d_in, const int* in_sizes, int n_in,
                              void* d_out, int out_size, void* d_ws, size_t ws_size,
                              hipStream_t stream) {
    const float* x    = (const float*)d_in[0];
    const float* Wf0  = (const float*)d_in[1];  const float* bf0 = (const float*)d_in[2];
    const float* Wi0  = (const float*)d_in[3];  const float* bi0 = (const float*)d_in[4];
    const float* Wh0  = (const float*)d_in[5];  const float* bh0 = (const float*)d_in[6];
    const float* Wf1  = (const float*)d_in[7];  const float* bf1 = (const float*)d_in[8];
    const float* Wi1  = (const float*)d_in[9];  const float* bi1 = (const float*)d_in[10];
    const float* Wh1  = (const float*)d_in[11]; const float* bh1 = (const float*)d_in[12];
    const float* ln_g = (const float*)d_in[13]; const float* ln_b = (const float*)d_in[14];
    const float* W_out = (const float*)d_in[15]; const float* b_out = (const float*)d_in[16];

    char* ws = (char*)d_ws;
    unsigned short* Xp = (unsigned short*)ws;  ws += (size_t)MROWS * DDIM * 2;   // 32 MB permuted X
    unsigned short* Wp = (unsigned short*)ws;  ws += (size_t)6 * DDIM * DDIM * 2; // 3 MB permuted W
    unsigned int* aubuf = (unsigned int*)ws;   ws += (size_t)MROWS * DDIM * 4;   // 64 MB packed a|u
    float* Asum = (float*)ws;  ws += (size_t)BSZ * NCHUNK * DDIM * 4;            // 1 MB
    float* Usum = (float*)ws;  ws += (size_t)BSZ * NCHUNK * DDIM * 4;
    float* Hinit = (float*)ws; ws += (size_t)BSZ * NCHUNK * DDIM * 4;
    unsigned short* h0p = (unsigned short*)ws; ws += (size_t)MROWS * DDIM * 2;   // 32 MB permuted h0

    const size_t GSTRIDE = (size_t)DDIM * DDIM;   // ushorts per gate block

    // cast+permute: 1024 X groups + 96 W groups
    cast_perm<<<1120, 256, 0, stream>>>(
        x, Wf0, Wi0, Wh0, Wf1, Wi1, Wh1, (uint4*)Xp, (uint4*)Wp);

    // ---- layer 0 ----
    gates_gemm<<<2048, 256, 0, stream>>>(Xp, Wp, Wp + GSTRIDE, Wp + 2 * GSTRIDE,
                                         bf0, bi0, bh0, aubuf, Asum, Usum);
    scan_pass2<<<32, 256, 0, stream>>>((const float4*)Asum, (const float4*)Usum, (float4*)Hinit);
    scan_pass3<<<128, 256, 0, stream>>>((const uint4*)aubuf, (const float4*)Hinit, (uint4*)h0p);

    // ---- layer 1 ----
    gates_gemm<<<2048, 256, 0, stream>>>(h0p, Wp + 3 * GSTRIDE, Wp + 4 * GSTRIDE, Wp + 5 * GSTRIDE,
                                         bf1, bi1, bh1, aubuf, Asum, Usum);
    scan_pass2<<<32, 256, 0, stream>>>((const float4*)Asum, (const float4*)Usum, (float4*)Hinit);
    scan3_final<<<512, 256, 0, stream>>>((const uint2*)aubuf, (const float2*)Hinit,
                                         (const float2*)x, ln_g, ln_b, W_out, b_out,
                                         (float*)d_out);
}

// Round 16
// 207.782 us; speedup vs baseline: 1.3588x; 1.0013x over previous
//
#include <hip/hip_runtime.h>
#include <hip/hip_bf16.h>
#include <stdint.h>

// B=8, T=4096, D=512, OUT=1. M = B*T = 32768.
// cast_perm (LDS-transposed); fused gates GEMM (fragment-major LDS, 0 conflicts,
// 4-phase K-tile schedule); hierarchical pass2; pass3 (permuted h0);
// scan3_final (2-phase LDS, 256 thr).
//
// Permuted layout (16B slots): S = (m>>5)*2048 + (k>>6)*256 + ((k>>3)&7)*32 + (m&31)

#define MROWS 32768
#define DDIM  512
#define TLEN  4096
#define BSZ   8
#define NCHUNK 64
#define CLEN   64

typedef __attribute__((ext_vector_type(8))) __bf16 bf16x8;
typedef __attribute__((ext_vector_type(16))) float f32x16;
typedef __attribute__((ext_vector_type(4))) unsigned short ushort4_t;
typedef __attribute__((ext_vector_type(2))) unsigned short ushort2_t;

static __device__ __forceinline__ unsigned short f2bf(float f) {
    unsigned int u = __float_as_uint(f);
    u = (u + 0x7FFFu + ((u >> 16) & 1u)) >> 16;   // RNE
    return (unsigned short)u;
}
static __device__ __forceinline__ void gload_lds16(const void* gptr, void* ldsp) {
    __builtin_amdgcn_global_load_lds(
        (const __attribute__((address_space(1))) uint32_t*)gptr,
        (__attribute__((address_space(3))) uint32_t*)ldsp,
        16, 0, 0);
}

#define WAITV(n) asm volatile("s_waitcnt vmcnt(" #n ")" ::: "memory")
#define WAITL0() asm volatile("s_waitcnt lgkmcnt(0)" ::: "memory")

// ---------------- cast + permute via LDS transpose ----------------
__global__ __launch_bounds__(256) void cast_perm(
    const float* __restrict__ x,
    const float* __restrict__ w0, const float* __restrict__ w1,
    const float* __restrict__ w2, const float* __restrict__ w3,
    const float* __restrict__ w4, const float* __restrict__ w5,
    uint4* __restrict__ xp, uint4* __restrict__ wp)
{
    __shared__ unsigned short t[32 * 520];   // 32.5 KB
    const int blk = blockIdx.x;              // 0..1119
    const int tid = threadIdx.x;
    const float* src;
    uint4* dst;
    if (blk < 1024) {
        src = x + (size_t)blk * 32 * 512;
        dst = xp + (size_t)blk * 2048;
    } else {
        int gb = blk - 1024;                 // 0..95: gate g, group Gn
        int g = gb >> 4;
        const float* w = (g == 0) ? w0 : (g == 1) ? w1 : (g == 2) ? w2
                       : (g == 3) ? w3 : (g == 4) ? w4 : w5;
        src = w + (size_t)(gb & 15) * 32 * 512;
        dst = wp + (size_t)gb * 2048;
    }
#pragma unroll
    for (int p = 0; p < 16; ++p) {
        int idx = p * 256 + tid;             // 0..4095
        int r = idx >> 7, c4 = idx & 127;
        float4 v = reinterpret_cast<const float4*>(src)[(size_t)r * 128 + c4];
        ushort4_t o;
        o.x = f2bf(v.x); o.y = f2bf(v.y); o.z = f2bf(v.z); o.w = f2bf(v.w);
        *reinterpret_cast<ushort4_t*>(&t[r * 520 + c4 * 4]) = o;
    }
    __syncthreads();
#pragma unroll
    for (int q = 0; q < 8; ++q) {
        int s = q * 256 + tid;               // 0..2047
        int Tk = s >> 8, c = (s >> 5) & 7, r = s & 31;
        uint4 o = *reinterpret_cast<const uint4*>(&t[r * 520 + Tk * 64 + c * 8]);
        dst[s] = o;
    }
}

// ---------------- fused gate GEMM + chunk-summary epilogue ----------------
// 256 thr / 4 waves (2m x 2n), wave 64x32 via 32x32x16 MFMA, BM=128 BN=64
// BK=64, ring-2 80KB, fragment-major LDS (linear staged + linear reads, 0
// conflicts). NEW: 4-phase K-tile schedule -- per phase {barrier; stage chunk
// (phases 0-2); 5 ds_read; lgkmcnt(0); setprio MFMA x6}; vmcnt(0) own-loads
// only at tile boundary (loads issued >=2 phases earlier).
// Hazards: stage into buf(t+1)=buf(t-1) issued only after a barrier that
// postdates all waves' t-1 lgkmcnt(0) (reads complete); tile-t reads gated by
// own vmcnt(0) + p0 barrier.
__global__ __launch_bounds__(256, 2) void gates_gemm(
    const unsigned short* __restrict__ X,     // permuted
    const unsigned short* __restrict__ Wf,    // permuted gate bases
    const unsigned short* __restrict__ Wi,
    const unsigned short* __restrict__ Wh,
    const float* __restrict__ bf_, const float* __restrict__ bi_,
    const float* __restrict__ bh_,
    unsigned int* __restrict__ au_out,
    float* __restrict__ Asum, float* __restrict__ Usum)
{
    __shared__ __align__(16) unsigned short lds[2 * 20480];   // 80 KB

    const int tid  = threadIdx.x;
    const int lane = tid & 63;
    const int wave = tid >> 6;                 // 0..3
    const int wm = wave >> 1;                  // 0..1 : 64-row strip (= one chunk)
    const int wn = wave & 1;                   // 0..1 : 32-col strip
    const int ln31 = lane & 31;
    const int kh = lane >> 5;

    const int w = blockIdx.x;
    const int xcd = w & 7;
    const int s = w >> 3;                      // 0..255
    const int by = xcd * 32 + (s >> 3);        // 0..255
    const int bx = s & 7;                      // 0..7
    const int mblk = by * 128;
    const int nblk = bx * 64;

    const int grA = mblk >> 5;
    const int gnB = nblk >> 5;
    const unsigned short* gA0 = X  + ((size_t)(grA + 0) * 2048 + tid) * 8;
    const unsigned short* gA1 = X  + ((size_t)(grA + 1) * 2048 + tid) * 8;
    const unsigned short* gA2 = X  + ((size_t)(grA + 2) * 2048 + tid) * 8;
    const unsigned short* gA3 = X  + ((size_t)(grA + 3) * 2048 + tid) * 8;
    const unsigned short* gF0 = Wf + ((size_t)(gnB + 0) * 2048 + tid) * 8;
    const unsigned short* gF1 = Wf + ((size_t)(gnB + 1) * 2048 + tid) * 8;
    const unsigned short* gI0 = Wi + ((size_t)(gnB + 0) * 2048 + tid) * 8;
    const unsigned short* gI1 = Wi + ((size_t)(gnB + 1) * 2048 + tid) * 8;
    const unsigned short* gH0 = Wh + ((size_t)(gnB + 0) * 2048 + tid) * 8;
    const unsigned short* gH1 = Wh + ((size_t)(gnB + 1) * 2048 + tid) * 8;

    const int tid8 = tid * 8;
    const int lane16 = lane * 8;               // linear read vaddr (ushorts)

    f32x16 accF[2], accI[2], accH[2];
#pragma unroll
    for (int mi = 0; mi < 2; ++mi) {
#pragma unroll
        for (int e = 0; e < 16; ++e) { accF[mi][e] = 0.f; accI[mi][e] = 0.f; accH[mi][e] = 0.f; }
    }

#define STAGE_C0(bb) do { \
    gload_lds16(gA0, lds + (bb) + tid8);         gA0 += 2048; \
    gload_lds16(gA1, lds + (bb) + 2048  + tid8); gA1 += 2048; \
    gload_lds16(gA2, lds + (bb) + 4096  + tid8); gA2 += 2048; \
    gload_lds16(gA3, lds + (bb) + 6144  + tid8); gA3 += 2048; } while (0)
#define STAGE_C1(bb) do { \
    gload_lds16(gF0, lds + (bb) + 8192  + tid8); gF0 += 2048; \
    gload_lds16(gF1, lds + (bb) + 10240 + tid8); gF1 += 2048; \
    gload_lds16(gI0, lds + (bb) + 12288 + tid8); gI0 += 2048; } while (0)
#define STAGE_C2(bb) do { \
    gload_lds16(gI1, lds + (bb) + 14336 + tid8); gI1 += 2048; \
    gload_lds16(gH0, lds + (bb) + 16384 + tid8); gH0 += 2048; \
    gload_lds16(gH1, lds + (bb) + 18432 + tid8); gH1 += 2048; } while (0)

    // prologue: stage tile 0 fully into buf0
    STAGE_C0(0); STAGE_C1(0); STAGE_C2(0);

#pragma unroll
    for (int t = 0; t < 8; ++t) {
        const unsigned short* cb = lds + (t & 1) * 20480;
        const int nbb = ((t + 1) & 1) * 20480;
#pragma unroll
        for (int p = 0; p < 4; ++p) {
            if (p == 0) { WAITV(0); }          // own tile-t loads landed
            __builtin_amdgcn_s_barrier();      // all waves' loads landed / reads done
            __builtin_amdgcn_sched_barrier(0);
            if (t < 7) {                       // stage tile t+1, spread over phases 0-2
                if (p == 0) STAGE_C0(nbb);
                else if (p == 1) STAGE_C1(nbb);
                else if (p == 2) STAGE_C2(nbb);
            }
            bf16x8 af0 = *reinterpret_cast<const bf16x8*>(cb + (wm * 8 + p) * 512 + lane16);
            bf16x8 bF  = *reinterpret_cast<const bf16x8*>(cb + 8192  + (wn * 4 + p) * 512 + lane16);
            bf16x8 af1 = *reinterpret_cast<const bf16x8*>(cb + (wm * 8 + 4 + p) * 512 + lane16);
            bf16x8 bI  = *reinterpret_cast<const bf16x8*>(cb + 12288 + (wn * 4 + p) * 512 + lane16);
            bf16x8 bH  = *reinterpret_cast<const bf16x8*>(cb + 16384 + (wn * 4 + p) * 512 + lane16);
            WAITL0();                          // cluster: all 5 reads done
            __builtin_amdgcn_sched_barrier(0); // rule 18: pin MFMAs after lgkmcnt
            __builtin_amdgcn_s_setprio(1);
            accF[0] = __builtin_amdgcn_mfma_f32_32x32x16_bf16(af0, bF, accF[0], 0, 0, 0);
            accF[1] = __builtin_amdgcn_mfma_f32_32x32x16_bf16(af1, bF, accF[1], 0, 0, 0);
            accI[0] = __builtin_amdgcn_mfma_f32_32x32x16_bf16(af0, bI, accI[0], 0, 0, 0);
            accI[1] = __builtin_amdgcn_mfma_f32_32x32x16_bf16(af1, bI, accI[1], 0, 0, 0);
            accH[0] = __builtin_amdgcn_mfma_f32_32x32x16_bf16(af0, bH, accH[0], 0, 0, 0);
            accH[1] = __builtin_amdgcn_mfma_f32_32x32x16_bf16(af1, bH, accH[1], 0, 0, 0);
            __builtin_amdgcn_s_setprio(0);
            __builtin_amdgcn_sched_barrier(0);
        }
    }
#undef STAGE_C0
#undef STAGE_C1
#undef STAGE_C2

    // ---- epilogue: gates + packed au + full-chunk summary ----
    const int n = nblk + wn * 32 + ln31;
    const float bfv = bf_[n], biv = bi_[n], bhv = bh_[n];
    const bool up = (lane & 32) != 0;
    float ca = 1.f, cu = 0.f;
#pragma unroll
    for (int mi = 0; mi < 2; ++mi) {
#pragma unroll
        for (int j = 0; j < 4; ++j) {
            float sa = 1.f, su = 0.f;
#pragma unroll
            for (int r = 0; r < 4; ++r) {
                const int reg = 4 * j + r;
                const int m = mblk + wm * 64 + mi * 32 + 8 * j + 4 * kh + r;
                float zf = accF[mi][reg] + bfv;
                float zi = accI[mi][reg] + biv;
                float zh = accH[mi][reg] + bhv;
                float ef = __expf(-zf);
                float ei = __expf(-zi);
                float inv = __frcp_rn(2.0f + ef + ei);
                float av = (1.0f + ei) * inv;
                float uv = (1.0f + ef) * inv * zh;
                au_out[(size_t)m * 512 + n] =
                    ((unsigned int)f2bf(uv) << 16) | (unsigned int)f2bf(av);
                su = av * su + uv; sa *= av;
            }
            float oa = __shfl_xor(sa, 32), ou = __shfl_xor(su, 32);
            float ta = sa * oa;
            float tu = up ? (sa * ou + su) : (oa * su + ou);
            cu = ta * cu + tu; ca = ca * ta;
        }
    }
    if (lane < 32) {
        size_t ci = (size_t)(by * 2 + wm) * 512 + n;
        Asum[ci] = ca;
        Usum[ci] = cu;
    }
}

// ---------------- chunk-prefix (pass2), hierarchical ----------------
__global__ __launch_bounds__(256) void scan_pass2(
    const float4* __restrict__ Asum, const float4* __restrict__ Usum,
    float4* __restrict__ Hinit)
{
    int gid = blockIdx.x * 256 + threadIdx.x;   // 0..8191
    int col = gid >> 3;                          // 0..1023 = b*128 + d4
    int t8  = gid & 7;
    int b = col >> 7, d4 = col & 127;
    int lane = threadIdx.x & 63;

    float4 a[8], u[8];
    float4 Ac = {1.f, 1.f, 1.f, 1.f}, Uc = {0.f, 0.f, 0.f, 0.f};
#pragma unroll
    for (int j = 0; j < 8; ++j) {
        size_t idx = (size_t)(b * 64 + t8 * 8 + j) * 128 + d4;
        a[j] = Asum[idx]; u[j] = Usum[idx];
        Uc.x = a[j].x * Uc.x + u[j].x; Uc.y = a[j].y * Uc.y + u[j].y;
        Uc.z = a[j].z * Uc.z + u[j].z; Uc.w = a[j].w * Uc.w + u[j].w;
        Ac.x *= a[j].x; Ac.y *= a[j].y; Ac.z *= a[j].z; Ac.w *= a[j].w;
    }
#pragma unroll
    for (int d = 1; d < 8; d <<= 1) {
        float4 Ao, Uo;
        Ao.x = __shfl(Ac.x, lane - d); Ao.y = __shfl(Ac.y, lane - d);
        Ao.z = __shfl(Ac.z, lane - d); Ao.w = __shfl(Ac.w, lane - d);
        Uo.x = __shfl(Uc.x, lane - d); Uo.y = __shfl(Uc.y, lane - d);
        Uo.z = __shfl(Uc.z, lane - d); Uo.w = __shfl(Uc.w, lane - d);
        if (t8 >= d) {
            Uc.x = Ac.x * Uo.x + Uc.x; Uc.y = Ac.y * Uo.y + Uc.y;
            Uc.z = Ac.z * Uo.z + Uc.z; Uc.w = Ac.w * Uo.w + Uc.w;
            Ac.x *= Ao.x; Ac.y *= Ao.y; Ac.z *= Ao.z; Ac.w *= Ao.w;
        }
    }
    float4 h;
    h.x = __shfl(Uc.x, lane - 1); h.y = __shfl(Uc.y, lane - 1);
    h.z = __shfl(Uc.z, lane - 1); h.w = __shfl(Uc.w, lane - 1);
    if (t8 == 0) { h.x = 0.f; h.y = 0.f; h.z = 0.f; h.w = 0.f; }
#pragma unroll
    for (int j = 0; j < 8; ++j) {
        size_t idx = (size_t)(b * 64 + t8 * 8 + j) * 128 + d4;
        Hinit[idx] = h;
        h.x = a[j].x * h.x + u[j].x; h.y = a[j].y * h.y + u[j].y;
        h.z = a[j].z * h.z + u[j].z; h.w = a[j].w * h.w + u[j].w;
    }
}

// ---------------- pass3 (layer 0): scan -> PERMUTED bf16 h0 ----------------
__global__ void scan_pass3(const uint4* __restrict__ au,
                           const float4* __restrict__ Hinit,
                           uint4* __restrict__ hp) {
    int gid = blockIdx.x * 256 + threadIdx.x;   // 0..32767
    int d8 = gid & 63;
    int c  = (gid >> 6) & 63;
    int b  = gid >> 12;
    const int base_m = b * TLEN + c * CLEN;
    size_t aubase = (size_t)base_m * 128 + d8 * 2;       // uint4 units
    size_t s4 = (size_t)(b * NCHUNK + c) * 128 + d8 * 2;
    float4 h0 = Hinit[s4], h1 = Hinit[s4 + 1];
    float h[8] = {h0.x, h0.y, h0.z, h0.w, h1.x, h1.y, h1.z, h1.w};
    const int Tk = d8 >> 3, cc = d8 & 7;
    for (int l = 0; l < CLEN; ++l) {
        int m = base_m + l;
        uint4 a0 = au[aubase + (size_t)l * 128];
        uint4 a1 = au[aubase + (size_t)l * 128 + 1];
        unsigned vv[8] = {a0.x, a0.y, a0.z, a0.w, a1.x, a1.y, a1.z, a1.w};
        unsigned ob[8];
#pragma unroll
        for (int j = 0; j < 8; ++j) {
            float av = __uint_as_float(vv[j] << 16);
            float uv = __uint_as_float(vv[j] & 0xFFFF0000u);
            h[j] = av * h[j] + uv;
            ob[j] = f2bf(h[j]);
        }
        uint4 o;
        o.x = ob[0] | (ob[1] << 16);
        o.y = ob[2] | (ob[3] << 16);
        o.z = ob[4] | (ob[5] << 16);
        o.w = ob[6] | (ob[7] << 16);
        int S = (m >> 5) * 2048 + Tk * 256 + cc * 32 + (m & 31);
        hp[S] = o;
    }
}

// ---------------- pass3+residual+LN+proj fused (layer 1), 2-phase 256thr ----
__global__ __launch_bounds__(256) void scan3_final(
    const uint2* __restrict__ au2, const float2* __restrict__ Hinit2,
    const float2* __restrict__ x2,
    const float* __restrict__ g, const float* __restrict__ bvec,
    const float* __restrict__ Wout, const float* __restrict__ bout,
    float* __restrict__ out)
{
    __shared__ unsigned short rl[64 * 512];    // 64 KB bf16 residuals
    const int blk = blockIdx.x;                // 0..511 = b*64 + c
    const int b = blk >> 6, c = blk & 63;
    const int d2 = threadIdx.x;                // 0..255 (2 d's each)

    float2 h0 = Hinit2[(size_t)blk * 256 + d2];
    float h[2] = {h0.x, h0.y};
    size_t base = ((size_t)b * TLEN + c * CLEN) * 256 + d2;

#pragma unroll 4
    for (int l = 0; l < CLEN; ++l) {
        size_t idx = base + (size_t)l * 256;
        uint2 v = au2[idx];
        float2 xr = x2[idx];
        const unsigned vv[2] = {v.x, v.y};
        const float xa[2] = {xr.x, xr.y};
        ushort2_t o;
#pragma unroll
        for (int j = 0; j < 2; ++j) {
            float av = __uint_as_float(vv[j] << 16);
            float uv = __uint_as_float(vv[j] & 0xFFFF0000u);
            h[j] = av * h[j] + uv;
            float hv = h[j];
            if (hv != hv) hv = xa[j];          // NaN fallback
            o[j] = f2bf(xa[j] + hv);
        }
        *reinterpret_cast<ushort2_t*>(&rl[l * 512 + d2 * 2]) = o;
    }
    __syncthreads();

    const int lane = threadIdx.x & 63;
    const int wv = threadIdx.x >> 6;           // 0..3
    float4 g0 = reinterpret_cast<const float4*>(g)[lane * 2];
    float4 g1 = reinterpret_cast<const float4*>(g)[lane * 2 + 1];
    float4 b0 = reinterpret_cast<const float4*>(bvec)[lane * 2];
    float4 b1 = reinterpret_cast<const float4*>(bvec)[lane * 2 + 1];
    float4 w0 = reinterpret_cast<const float4*>(Wout)[lane * 2];
    float4 w1 = reinterpret_cast<const float4*>(Wout)[lane * 2 + 1];
    const float gg[8] = {g0.x, g0.y, g0.z, g0.w, g1.x, g1.y, g1.z, g1.w};
    const float bb[8] = {b0.x, b0.y, b0.z, b0.w, b1.x, b1.y, b1.z, b1.w};
    const float ww[8] = {w0.x, w0.y, w0.z, w0.w, w1.x, w1.y, w1.z, w1.w};
    const float bo = bout[0];

    for (int rr = 0; rr < 16; ++rr) {
        const int row = wv * 16 + rr;
        uint4 rv = *reinterpret_cast<const uint4*>(&rl[row * 512 + lane * 8]);
        const unsigned rw[4] = {rv.x, rv.y, rv.z, rv.w};
        float r[8];
#pragma unroll
        for (int j = 0; j < 4; ++j) {
            r[2 * j]     = __uint_as_float(rw[j] << 16);
            r[2 * j + 1] = __uint_as_float(rw[j] & 0xFFFF0000u);
        }
        float s = 0.f, q = 0.f;
#pragma unroll
        for (int j = 0; j < 8; ++j) { s += r[j]; q += r[j] * r[j]; }
#pragma unroll
        for (int m = 32; m >= 1; m >>= 1) {
            s += __shfl_xor(s, m);
            q += __shfl_xor(q, m);
        }
        float mu = s * (1.0f / 512.0f);
        float var = q * (1.0f / 512.0f) - mu * mu;
        float rstd = rsqrtf(var + 1e-5f);
        float p = 0.f;
#pragma unroll
        for (int j = 0; j < 8; ++j)
            p += ((r[j] - mu) * rstd * gg[j] + bb[j]) * ww[j];
#pragma unroll
        for (int m = 32; m >= 1; m >>= 1) p += __shfl_xor(p, m);
        if (lane == 0)
            out[(size_t)b * TLEN + c * CLEN + row] = p + bo;
    }
}

extern "C" void kernel_launch(void* const* d_in, const int* in_sizes, int n_in,
                              void* d_out, int out_size, void* d_ws, size_t ws_size,
                              hipStream_t stream) {
    const float* x    = (const float*)d_in[0];
    const float* Wf0  = (const float*)d_in[1];  const float* bf0 = (const float*)d_in[2];
    const float* Wi0  = (const float*)d_in[3];  const float* bi0 = (const float*)d_in[4];
    const float* Wh0  = (const float*)d_in[5];  const float* bh0 = (const float*)d_in[6];
    const float* Wf1  = (const float*)d_in[7];  const float* bf1 = (const float*)d_in[8];
    const float* Wi1  = (const float*)d_in[9];  const float* bi1 = (const float*)d_in[10];
    const float* Wh1  = (const float*)d_in[11]; const float* bh1 = (const float*)d_in[12];
    const float* ln_g = (const float*)d_in[13]; const float* ln_b = (const float*)d_in[14];
    const float* W_out = (const float*)d_in[15]; const float* b_out = (const float*)d_in[16];

    char* ws = (char*)d_ws;
    unsigned short* Xp = (unsigned short*)ws;  ws += (size_t)MROWS * DDIM * 2;   // 32 MB permuted X
    unsigned short* Wp = (unsigned short*)ws;  ws += (size_t)6 * DDIM * DDIM * 2; // 3 MB permuted W
    unsigned int* aubuf = (unsigned int*)ws;   ws += (size_t)MROWS * DDIM * 4;   // 64 MB packed a|u
    float* Asum = (float*)ws;  ws += (size_t)BSZ * NCHUNK * DDIM * 4;            // 1 MB
    float* Usum = (float*)ws;  ws += (size_t)BSZ * NCHUNK * DDIM * 4;
    float* Hinit = (float*)ws; ws += (size_t)BSZ * NCHUNK * DDIM * 4;
    unsigned short* h0p = (unsigned short*)ws; ws += (size_t)MROWS * DDIM * 2;   // 32 MB permuted h0

    const size_t GSTRIDE = (size_t)DDIM * DDIM;   // ushorts per gate block

    // cast+permute: 1024 X groups + 96 W groups
    cast_perm<<<1120, 256, 0, stream>>>(
        x, Wf0, Wi0, Wh0, Wf1, Wi1, Wh1, (uint4*)Xp, (uint4*)Wp);

    // ---- layer 0 ----
    gates_gemm<<<2048, 256, 0, stream>>>(Xp, Wp, Wp + GSTRIDE, Wp + 2 * GSTRIDE,
                                         bf0, bi0, bh0, aubuf, Asum, Usum);
    scan_pass2<<<32, 256, 0, stream>>>((const float4*)Asum, (const float4*)Usum, (float4*)Hinit);
    scan_pass3<<<128, 256, 0, stream>>>((const uint4*)aubuf, (const float4*)Hinit, (uint4*)h0p);

    // ---- layer 1 ----
    gates_gemm<<<2048, 256, 0, stream>>>(h0p, Wp + 3 * GSTRIDE, Wp + 4 * GSTRIDE, Wp + 5 * GSTRIDE,
                                         bf1, bi1, bh1, aubuf, Asum, Usum);
    scan_pass2<<<32, 256, 0, stream>>>((const float4*)Asum, (const float4*)Usum, (float4*)Hinit);
    scan3_final<<<512, 256, 0, stream>>>((const uint2*)aubuf, (const float2*)Hinit,
                                         (const float2*)x, ln_g, ln_b, W_out, b_out,
                                         (float*)d_out);
}